// Round 7
// baseline (174.071 us; speedup 1.0000x reference)
//
#include <hip/hip_runtime.h>
#include <hip/hip_bf16.h>

#define B_ROWS 16384
#define DDIM   512
#define NNODES 1023
#define NLEAF  1024
#define ODIM   256
#define LAMDA  1e-3
#define EPSV   1e-7f

typedef __bf16 bf16x8v __attribute__((ext_vector_type(8)));
typedef _Float16 f16x8 __attribute__((ext_vector_type(8)));
typedef float  f32x16v __attribute__((ext_vector_type(16)));

__device__ __forceinline__ float bf2f(unsigned short u) {
    return __uint_as_float(((unsigned)u) << 16);
}

// async global->LDS 16B copy (dst linear: wave-uniform base + lane*16)
__device__ __forceinline__ void gload16h(const _Float16* g, _Float16* l) {
    __builtin_amdgcn_global_load_lds(
        (const __attribute__((address_space(1))) unsigned int*)g,
        (__attribute__((address_space(3))) unsigned int*)l, 16, 0, 0);
}
__device__ __forceinline__ void gload16b(const __hip_bfloat16* g, __hip_bfloat16* l) {
    __builtin_amdgcn_global_load_lds(
        (const __attribute__((address_space(1))) unsigned int*)g,
        (__attribute__((address_space(3))) unsigned int*)l, 16, 0, 0);
}

// ---------------------------------------------------------------------------
// prep_all: merged prep_data (blocks 0..4095) + prep_w (blocks 4096..4351).
// data f32 -> Dh,Dl fp16 fragment-tiled [by(128)][ks(32)][tl(4)][lane(64)][8];
// W cols 1..512 -> Wh,Wl fp16 tiled [nb(8)][ks(32)][tm(4)][64][8].
// Split: a = ah + al/2048 (al pre-scaled by 2048 into fp16 normal range).
// ---------------------------------------------------------------------------
__global__ __launch_bounds__(256)
void prep_all(const float* __restrict__ data, const float* __restrict__ W,
              _Float16* __restrict__ Dh, _Float16* __restrict__ Dl,
              _Float16* __restrict__ Wh, _Float16* __restrict__ Wl)
{
    if (blockIdx.x < 4096) {
        int idx = blockIdx.x * 256 + threadIdx.x;
        int b  = idx >> 6;
        int k8 = idx & 63;
        const float4 v0 = *reinterpret_cast<const float4*>(&data[(size_t)b * DDIM + k8 * 8]);
        const float4 v1 = *reinterpret_cast<const float4*>(&data[(size_t)b * DDIM + k8 * 8 + 4]);
        float a[8] = {v0.x, v0.y, v0.z, v0.w, v1.x, v1.y, v1.z, v1.w};
        __align__(16) _Float16 h[8], l[8];
#pragma unroll
        for (int j = 0; j < 8; ++j) {
            h[j] = (_Float16)a[j];
            l[j] = (_Float16)((a[j] - (float)h[j]) * 2048.f);
        }
        int by = b >> 7, tl = (b >> 5) & 3, ln = (b & 31) | ((k8 & 1) << 5), ks = k8 >> 1;
        size_t off = ((((size_t)by * 32 + ks) * 4 + tl) * 64 + ln) * 8;
        *reinterpret_cast<ulonglong2*>(&Dh[off]) = *reinterpret_cast<const ulonglong2*>(h);
        *reinterpret_cast<ulonglong2*>(&Dl[off]) = *reinterpret_cast<const ulonglong2*>(l);
    } else {
        int idx = (blockIdx.x - 4096) * 256 + threadIdx.x;
        int t  = idx & 255;
        int ks = (idx >> 8) & 31;
        int nb = idx >> 13;
        int tm = t >> 6, ln = t & 63;
        int node = nb * 128 + tm * 32 + (ln & 31);
        int k = ks * 16 + (ln >> 5) * 8;
        __align__(16) _Float16 h[8], l[8];
        if (node < NNODES) {
#pragma unroll
            for (int j = 0; j < 8; ++j) {
                float a = W[(size_t)node * 513 + 1 + k + j];
                h[j] = (_Float16)a;
                l[j] = (_Float16)((a - (float)h[j]) * 2048.f);
            }
        } else {
#pragma unroll
            for (int j = 0; j < 8; ++j) { h[j] = (_Float16)0.f; l[j] = (_Float16)0.f; }
        }
        size_t off = (size_t)idx * 8;
        *reinterpret_cast<ulonglong2*>(&Wh[off]) = *reinterpret_cast<const ulonglong2*>(h);
        *reinterpret_cast<ulonglong2*>(&Wl[off]) = *reinterpret_cast<const ulonglong2*>(l);
    }
}

// ---------------------------------------------------------------------------
// GEMM1 fp16-split MFMA, BK=32. Wh/Wl/Dh staged via global_load_lds (48KB
// dbuf LDS); Dl read DIRECT global->VGPR (cuts LDS traffic 25%, balances
// LDS pipe vs vmem pipe). Counted vmcnt(10) = 6 staging + 4 Dl in flight.
// ---------------------------------------------------------------------------
__global__ __launch_bounds__(256, 2)
void gemm1_mfma(const _Float16* __restrict__ Wh, const _Float16* __restrict__ Wl,
                const _Float16* __restrict__ Dh, const _Float16* __restrict__ Dl,
                const float* __restrict__ W, const float* __restrict__ beta,
                float* __restrict__ PT)
{
    __shared__ _Float16 lds[2][3][4096];   // 48KB: [buf][Wh,Wl,Dh]
    const int tid = threadIdx.x;
    const int lane = tid & 63;
    const int wv = tid >> 6;
    const int wm = wv & 1, wn = wv >> 1;
    const int id = blockIdx.x;
    const int xcd = id & 7, slot = id >> 3;
    const int bx = slot & 7;
    const int by = xcd * 16 + (slot >> 3);
    const size_t wofs = (size_t)bx * 65536 + tid * 8;
    const size_t dofs = (size_t)by * 65536 + tid * 8;
    const int t16 = tid * 8;
    // direct-Dl fragment base for this wave
    const _Float16* dlp = Dl + (size_t)by * 65536 + (wn * 2) * 512 + lane * 8;

    f32x16v acc_h[2][2] = {};
    f32x16v acc_l[2][2] = {};

#define STAGE6(buf, tt) do { \
        const size_t so = (size_t)(tt) * 4096; \
        gload16h(Wh + wofs + so,        &lds[buf][0][t16]); \
        gload16h(Wh + wofs + so + 2048, &lds[buf][0][2048 + t16]); \
        gload16h(Wl + wofs + so,        &lds[buf][1][t16]); \
        gload16h(Wl + wofs + so + 2048, &lds[buf][1][2048 + t16]); \
        gload16h(Dh + dofs + so,        &lds[buf][2][t16]); \
        gload16h(Dh + dofs + so + 2048, &lds[buf][2][2048 + t16]); \
    } while (0)

    f16x8 Xdl[2][2], Ydl[2][2];

    // prologue: stage tile 0 + load its Dl frags
    STAGE6(0, 0);
#pragma unroll
    for (int kcl = 0; kcl < 2; ++kcl)
#pragma unroll
        for (int j = 0; j < 2; ++j)
            Xdl[kcl][j] = *reinterpret_cast<const f16x8*>(dlp + kcl * 2048 + j * 512);

    for (int t = 0; t < 16; ++t) {
        const int cur = t & 1;
        if (t + 1 < 16) {
            STAGE6(cur ^ 1, t + 1);
#pragma unroll
            for (int kcl = 0; kcl < 2; ++kcl)
#pragma unroll
                for (int j = 0; j < 2; ++j)
                    Ydl[kcl][j] = *reinterpret_cast<const f16x8*>(
                        dlp + (size_t)(t + 1) * 4096 + kcl * 2048 + j * 512);
            asm volatile("s_waitcnt vmcnt(10)" ::: "memory");
        } else {
            asm volatile("s_waitcnt vmcnt(0)" ::: "memory");
        }
        __builtin_amdgcn_s_barrier();

        f16x8 ah[2][2], al[2][2], bh[2][2];
#pragma unroll
        for (int kcl = 0; kcl < 2; ++kcl)
#pragma unroll
            for (int i = 0; i < 2; ++i) {
                int ao = kcl * 2048 + (wm * 2 + i) * 512 + lane * 8;
                int bo = kcl * 2048 + (wn * 2 + i) * 512 + lane * 8;
                ah[kcl][i] = *reinterpret_cast<const f16x8*>(&lds[cur][0][ao]);
                al[kcl][i] = *reinterpret_cast<const f16x8*>(&lds[cur][1][ao]);
                bh[kcl][i] = *reinterpret_cast<const f16x8*>(&lds[cur][2][bo]);
            }
        __builtin_amdgcn_s_setprio(1);
#pragma unroll
        for (int kcl = 0; kcl < 2; ++kcl)
#pragma unroll
            for (int i = 0; i < 2; ++i)
#pragma unroll
                for (int j = 0; j < 2; ++j) {
                    acc_h[i][j] = __builtin_amdgcn_mfma_f32_32x32x16_f16(ah[kcl][i], bh[kcl][j], acc_h[i][j], 0, 0, 0);
                    acc_l[i][j] = __builtin_amdgcn_mfma_f32_32x32x16_f16(ah[kcl][i], Xdl[kcl][j], acc_l[i][j], 0, 0, 0);
                    acc_l[i][j] = __builtin_amdgcn_mfma_f32_32x32x16_f16(al[kcl][i], bh[kcl][j], acc_l[i][j], 0, 0, 0);
                }
        __builtin_amdgcn_s_setprio(0);
        asm volatile("s_waitcnt lgkmcnt(0)" ::: "memory");
        __builtin_amdgcn_s_barrier();
#pragma unroll
        for (int kcl = 0; kcl < 2; ++kcl)
#pragma unroll
            for (int j = 0; j < 2; ++j)
                Xdl[kcl][j] = Ydl[kcl][j];
    }
#undef STAGE6

    // epilogue: z -> sigmoid -> PT[node][batch]
#pragma unroll
    for (int i = 0; i < 2; ++i) {
#pragma unroll
        for (int r = 0; r < 16; ++r) {
            int node = bx * 128 + wm * 64 + i * 32 + ((r & 3) + 8 * (r >> 2) + 4 * (lane >> 5));
            if (node < NNODES) {
                float w0 = W[(size_t)node * 513];
                float bt = beta[node];
#pragma unroll
                for (int j = 0; j < 2; ++j) {
                    float z = acc_h[i][j][r] + acc_l[i][j][r] * 4.8828125e-4f;
                    float s = bt * (z + w0);
                    float p = 1.f / (1.f + expf(-s));
                    PT[(size_t)node * B_ROWS + by * 128 + wn * 64 + j * 32 + (lane & 31)] = p;
                }
            }
        }
    }
}

// ---------------------------------------------------------------------------
// Tree pass: thread = row, one subtree-pair per block, fragment-tiled MU2 out.
// MU2 layout [mb(128)][kc(64)][mt(4)][lane(64)][8]:
//   row = mb*128+mt*32+(ln&31), leaf = kc*16+(ln>>5)*8+j
// ---------------------------------------------------------------------------
__global__ __launch_bounds__(256, 4)
void tree_pass(const float* __restrict__ PT,
               __hip_bfloat16* __restrict__ MU2,
               float* __restrict__ pval,          // [16][16384]
               int*   __restrict__ pidx)          // [16][16384]
{
    const int tid = threadIdx.x;
    const int rb = blockIdx.x & 63;
    const int g  = blockIdx.x >> 6;        // pair 0..15
    const int b  = rb * 256 + tid;

    const int c4 = 15 + g;
    const int n3 = (c4 - 1) >> 1;
    const int n2 = (n3 - 1) >> 1;
    const int n1 = (n2 - 1) >> 1;
    const float pc4 = PT[(size_t)c4 * B_ROWS + b];
    const float pn3 = PT[(size_t)n3 * B_ROWS + b];
    const float pn2 = PT[(size_t)n2 * B_ROWS + b];
    const float pn1 = PT[(size_t)n1 * B_ROWS + b];
    const float pn0 = PT[b];
    float pre = ((c4 & 1) ? pn3 : 1.f - pn3)
              * ((n3 & 1) ? pn2 : 1.f - pn2)
              * ((n2 & 1) ? pn1 : 1.f - pn1)
              * ((n1 & 1) ? pn0 : 1.f - pn0);
    float root[2] = { pre * pc4, pre * (1.f - pc4) };

    __align__(16) __hip_bfloat16 mbv[64];
    float bestv = -1.f; int besti = 0;
#pragma unroll
    for (int ss = 0; ss < 2; ++ss) {
        const int t = 2 * g + ss;
        float s[32];
#pragma unroll
        for (int u = 1; u < 32; ++u) {
            int lvl = 31 - __clz(u);
            int node = ((32 << lvl) - 1) + t * (1 << lvl) + (u - (1 << lvl));
            s[u] = PT[(size_t)node * B_ROWS + b];
        }
        float w[64];
        w[1] = root[ss];
#pragma unroll
        for (int u = 1; u < 32; ++u) {
            w[2 * u]     = w[u] * s[u];
            w[2 * u + 1] = w[u] * (1.f - s[u]);
        }
#pragma unroll
        for (int q = 0; q < 32; ++q) {
            float lv = w[32 + q];
            mbv[ss * 32 + q] = __float2bfloat16(lv);
            if (lv > bestv) { bestv = lv; besti = t * 32 + q; }
        }
    }
    // scatter into fragment-tiled MU2: 8x 16B coalesced stores
    {
        const int mb_ = b >> 7, mt_ = (b >> 5) & 3, lnlo = b & 31;
        const ulonglong2* src = reinterpret_cast<const ulonglong2*>(mbv);
#pragma unroll
        for (int c = 0; c < 4; ++c) {
            size_t base16 = (((size_t)mb_ * 64 + g * 4 + c) * 4 + mt_) * 64;
            *reinterpret_cast<ulonglong2*>(&MU2[(base16 + lnlo) * 8])      = src[c * 2];
            *reinterpret_cast<ulonglong2*>(&MU2[(base16 + 32 + lnlo) * 8]) = src[c * 2 + 1];
        }
    }
    pval[(size_t)g * B_ROWS + b] = bestv;
    pidx[(size_t)g * B_ROWS + b] = besti;
}

// ---------------------------------------------------------------------------
// colsum on MU2: grid 256 = kc(64) x mbg(4); block reduces 16 leaves over
// 4096 rows -> partial[mbg][1024]. No atomics.
// ---------------------------------------------------------------------------
__global__ __launch_bounds__(256)
void colsum(const __hip_bfloat16* __restrict__ MU2, float* __restrict__ partial)
{
    __shared__ float red[4][2][8];
    const int blk = blockIdx.x;
    const int kc = blk >> 2, mbg = blk & 3;
    const int t = threadIdx.x;
    const int w = t >> 6, ln = t & 63;
    float a[8] = {0.f, 0.f, 0.f, 0.f, 0.f, 0.f, 0.f, 0.f};
    for (int it = 0; it < 32; ++it) {
        int it2 = it * 4 + w;
        int mb = mbg * 32 + (it2 >> 2), mt = it2 & 3;
        size_t a16 = (((size_t)mb * 64 + kc) * 4 + mt) * 64 + ln;
        ulonglong2 u = *reinterpret_cast<const ulonglong2*>(&MU2[a16 * 8]);
        const unsigned short* hs = reinterpret_cast<const unsigned short*>(&u);
#pragma unroll
        for (int j = 0; j < 8; ++j) a[j] += bf2f(hs[j]);
    }
#pragma unroll
    for (int m = 1; m < 32; m <<= 1)
#pragma unroll
        for (int j = 0; j < 8; ++j) a[j] += __shfl_xor(a[j], m, 64);
    if ((ln & 31) == 0) {
#pragma unroll
        for (int j = 0; j < 8; ++j) red[w][ln >> 5][j] = a[j];
    }
    __syncthreads();
    if (t < 16) {
        float s = red[0][t >> 3][t & 7] + red[1][t >> 3][t & 7]
                + red[2][t >> 3][t & 7] + red[3][t >> 3][t & 7];
        partial[(size_t)mbg * NLEAF + kc * 16 + t] = s;
    }
}

// ---------------------------------------------------------------------------
// softmax over param rows -> logdist (f32) + DT2 (bf16 fragment-tiled
// [kc(64)][nt(8)][lane(64)][8]: col=nt*32+(ln&31), leaf=kc*16+(ln>>5)*8+j)
// ---------------------------------------------------------------------------
__global__ __launch_bounds__(256)
void softmax_param(const float* __restrict__ param,
                   float* __restrict__ logdist,
                   __hip_bfloat16* __restrict__ DT2)
{
    __shared__ float red[4], red2[4];
    int l = blockIdx.x;
    int o = threadIdx.x;
    float x = param[(size_t)l * ODIM + o];
    float m = x;
#pragma unroll
    for (int s = 1; s < 64; s <<= 1) m = fmaxf(m, __shfl_xor(m, s, 64));
    if ((o & 63) == 0) red[o >> 6] = m;
    __syncthreads();
    m = fmaxf(fmaxf(red[0], red[1]), fmaxf(red[2], red[3]));
    float e = expf(x - m);
    float s = e;
#pragma unroll
    for (int k = 1; k < 64; k <<= 1) s += __shfl_xor(s, k, 64);
    if ((o & 63) == 0) red2[o >> 6] = s;
    __syncthreads();
    s = red2[0] + red2[1] + red2[2] + red2[3];
    float d = e / s;
    logdist[(size_t)l * ODIM + o] = logf(d);
    int kc = l >> 4, kk = l & 15;
    int lane = (o & 31) | ((kk >> 3) << 5);
    DT2[(((size_t)kc * 8 + (o >> 5)) * 64 + lane) * 8 + (kk & 7)] = __float2bfloat16(d);
}

// ---------------------------------------------------------------------------
// penalty: reduce 4 partials, heap-aggregate, sum log terms.
// ---------------------------------------------------------------------------
__global__ __launch_bounds__(256)
void penalty_kernel(const float* __restrict__ partial, float* __restrict__ out_pen)
{
    __shared__ float M[2048];
    __shared__ double dred[256];
    int tid = threadIdx.x;
    for (int i = tid; i < 1024; i += 256)
        M[1024 + i] = partial[i] + partial[NLEAF + i] + partial[2 * NLEAF + i] + partial[3 * NLEAF + i];
    __syncthreads();
    for (int n = 512; n >= 1; n >>= 1) {
        for (int u = n + tid; u < 2 * n; u += 256) M[u] = M[2 * u] + M[2 * u + 1];
        __syncthreads();
    }
    double acc = 0.0;
    for (int u = 2 + tid; u < 2048; u += 256) {
        int lvl = 31 - __clz(u);
        float a = M[u] / (M[u >> 1] + EPSV);
        a = fminf(fmaxf(a, EPSV), 1.f - EPSV);
        float term = logf(a) + logf(1.f - a);
        acc -= ldexp((double)LAMDA * 0.5, 1 - lvl) * (double)term;
    }
    dred[tid] = acc;
    __syncthreads();
    for (int s = 128; s > 0; s >>= 1) {
        if (tid < s) dred[tid] += dred[tid + s];
        __syncthreads();
    }
    if (tid == 0) out_pen[0] = (float)dred[0];
}

// ---------------------------------------------------------------------------
// GEMM2: out1 = log(MU2 @ DT2), M-tile 64, N=256, BK=32, dbuf gload_lds.
// grid 256, 4 waves; wave w covers cols w*64..w*64+63 (Mf=2,Nf=2).
// ---------------------------------------------------------------------------
__global__ __launch_bounds__(256)
void gemm2_log(const __hip_bfloat16* __restrict__ MU2,
               const __hip_bfloat16* __restrict__ DT2,
               float* __restrict__ out1)
{
    __shared__ __hip_bfloat16 ldsA[2][2048];   // 2 x 4KB
    __shared__ __hip_bfloat16 ldsB[2][8192];   // 2 x 16KB (two kc slices)
    const int tid = threadIdx.x;
    const int lane = tid & 63;
    const int w = tid >> 6;
    const int blk = blockIdx.x;
    const int m0 = blk * 64;
    const int mb = blk >> 1;
    const int mtbase = (blk & 1) * 2;
    const int s_kcl = tid >> 7, s_mti = (tid >> 6) & 1, s_ln = tid & 63;

    f32x16v acc[2][2] = {};

#define STAGE2(buf, kc0) do { \
        size_t sa16 = (((size_t)mb * 64 + (kc0) + s_kcl) * 4 + mtbase + s_mti) * 64 + s_ln; \
        gload16b(MU2 + sa16 * 8, &ldsA[buf][tid * 8]); \
        gload16b(DT2 + ((size_t)(kc0) * 512 + tid) * 8,             &ldsB[buf][tid * 8]); \
        gload16b(DT2 + ((size_t)(kc0) * 512 + 256 + tid) * 8,       &ldsB[buf][2048 + tid * 8]); \
        gload16b(DT2 + ((size_t)((kc0) + 1) * 512 + tid) * 8,       &ldsB[buf][4096 + tid * 8]); \
        gload16b(DT2 + ((size_t)((kc0) + 1) * 512 + 256 + tid) * 8, &ldsB[buf][6144 + tid * 8]); \
    } while (0)

    STAGE2(0, 0);
    for (int it = 0; it < 32; ++it) {
        const int cur = it & 1;
        if (it + 1 < 32) {
            STAGE2(cur ^ 1, 2 * (it + 1));
            asm volatile("s_waitcnt vmcnt(5)" ::: "memory");
        } else {
            asm volatile("s_waitcnt vmcnt(0)" ::: "memory");
        }
        __builtin_amdgcn_s_barrier();
        bf16x8v a[2][2], bb[2][2];
#pragma unroll
        for (int kcl = 0; kcl < 2; ++kcl)
#pragma unroll
            for (int i = 0; i < 2; ++i) {
                a[kcl][i]  = *reinterpret_cast<const bf16x8v*>(&ldsA[cur][((kcl * 2 + i) * 64 + lane) * 8]);
                bb[kcl][i] = *reinterpret_cast<const bf16x8v*>(&ldsB[cur][((kcl * 8 + 2 * w + i) * 64 + lane) * 8]);
            }
        __builtin_amdgcn_s_setprio(1);
#pragma unroll
        for (int kcl = 0; kcl < 2; ++kcl)
#pragma unroll
            for (int i = 0; i < 2; ++i)
#pragma unroll
                for (int j = 0; j < 2; ++j)
                    acc[i][j] = __builtin_amdgcn_mfma_f32_32x32x16_bf16(a[kcl][i], bb[kcl][j], acc[i][j], 0, 0, 0);
        __builtin_amdgcn_s_setprio(0);
        asm volatile("s_waitcnt lgkmcnt(0)" ::: "memory");
        __builtin_amdgcn_s_barrier();
    }
#undef STAGE2
#pragma unroll
    for (int i = 0; i < 2; ++i)
#pragma unroll
        for (int j = 0; j < 2; ++j)
#pragma unroll
            for (int r = 0; r < 16; ++r) {
                int row = m0 + i * 32 + (r & 3) + 8 * (r >> 2) + 4 * (lane >> 5);
                int col = w * 64 + j * 32 + (lane & 31);
                out1[(size_t)row * ODIM + col] = logf(acc[i][j][r]);
            }
}

// ---------------------------------------------------------------------------
// fused argmax over 16 partials + gather of logdist rows.
// ---------------------------------------------------------------------------
__global__ __launch_bounds__(256)
void argmax_gather(const float* __restrict__ pval, const int* __restrict__ pidx,
                   const float* __restrict__ logdist, float* __restrict__ out0)
{
    __shared__ int sid[64];
    const int blk = blockIdx.x;      // 256 blocks x 64 rows
    const int t = threadIdx.x;
    if (t < 64) {
        int row = blk * 64 + t;
        float bv = -1.f; int bi = 0;
        for (int g = 0; g < 16; ++g) {
            float v = pval[(size_t)g * B_ROWS + row];
            if (v > bv) { bv = v; bi = pidx[(size_t)g * B_ROWS + row]; }
        }
        sid[t] = bi;
    }
    __syncthreads();
    for (int rr = 0; rr < 64; ++rr) {
        int id = sid[rr];
        out0[(size_t)(blk * 64 + rr) * ODIM + t] = logdist[(size_t)id * ODIM + t];
    }
}

__global__ void copy_w(const float* __restrict__ W, float* __restrict__ outW)
{
    int i = blockIdx.x * 256 + threadIdx.x;
    if (i < NNODES * 513) outW[i] = W[i];
}

// ---------------------------------------------------------------------------
extern "C" void kernel_launch(void* const* d_in, const int* in_sizes, int n_in,
                              void* d_out, int out_size, void* d_ws, size_t ws_size,
                              hipStream_t stream)
{
    (void)in_sizes; (void)n_in; (void)out_size; (void)ws_size;
    const float* data  = (const float*)d_in[0];
    const float* W     = (const float*)d_in[1];
    const float* beta  = (const float*)d_in[2];
    const float* param = (const float*)d_in[3];
    float* out = (float*)d_out;

    char* ws = (char*)d_ws;
    size_t off = 0;
    float* PT = (float*)(ws + off);                   off += (size_t)NNODES * B_ROWS * 4;   // 67.04 MB
    char* X = ws + off;                               off += 2 * 1048576 + 2 * 16777216;    // 35.65 MB
    _Float16* Wh = (_Float16*)(X);
    _Float16* Wl = (_Float16*)(X + 1048576);
    _Float16* Dh = (_Float16*)(X + 2 * 1048576);
    _Float16* Dl = (_Float16*)(X + 2 * 1048576 + 16777216);
    __hip_bfloat16* MU2 = (__hip_bfloat16*)(X + 2 * 1048576);  // overlays Dh+Dl (33.55 MB)
    __hip_bfloat16* DT2 = (__hip_bfloat16*)(ws + off); off += (size_t)ODIM * NLEAF * 2;
    float* logdist = (float*)(ws + off);              off += (size_t)NLEAF * ODIM * 4;
    float* partial = (float*)(ws + off);              off += (size_t)4 * NLEAF * 4;
    float* pval    = (float*)(ws + off);              off += (size_t)16 * B_ROWS * 4;
    int*   pidx    = (int*)(ws + off);                off += (size_t)16 * B_ROWS * 4;

    float* out_logpred = out;
    float* out_logout  = out + (size_t)B_ROWS * ODIM;
    float* out_pen     = out + 2 * (size_t)B_ROWS * ODIM;
    float* out_W       = out_pen + 1;

    prep_all<<<4352, 256, 0, stream>>>(data, W, Dh, Dl, Wh, Wl);
    softmax_param<<<NLEAF, 256, 0, stream>>>(param, logdist, DT2);

    gemm1_mfma<<<1024, 256, 0, stream>>>(Wh, Wl, Dh, Dl, W, beta, PT);

    tree_pass<<<1024, 256, 0, stream>>>(PT, MU2, pval, pidx);
    colsum<<<256, 256, 0, stream>>>(MU2, partial);
    penalty_kernel<<<1, 256, 0, stream>>>(partial, out_pen);

    gemm2_log<<<B_ROWS / 64, 256, 0, stream>>>(MU2, DT2, out_logout);
    argmax_gather<<<B_ROWS / 64, 256, 0, stream>>>(pval, pidx, logdist, out_logpred);
    copy_w<<<(NNODES * 513 + 255) / 256, 256, 0, stream>>>(W, out_W);
}

// Round 8
// 161.965 us; speedup vs baseline: 1.0747x; 1.0747x over previous
//
#include <hip/hip_runtime.h>
#include <hip/hip_bf16.h>

#define B_ROWS 16384
#define DDIM   512
#define NNODES 1023
#define NLEAF  1024
#define ODIM   256
#define LAMDA  1e-3
#define EPSV   1e-7f

typedef __bf16 bf16x8v __attribute__((ext_vector_type(8)));
typedef _Float16 f16x8 __attribute__((ext_vector_type(8)));
typedef float  f32x16v __attribute__((ext_vector_type(16)));

__device__ __forceinline__ float bf2f(unsigned short u) {
    return __uint_as_float(((unsigned)u) << 16);
}

// async global->LDS 16B copy (dst linear: wave-uniform base + lane*16)
__device__ __forceinline__ void gload16h(const _Float16* g, _Float16* l) {
    __builtin_amdgcn_global_load_lds(
        (const __attribute__((address_space(1))) unsigned int*)g,
        (__attribute__((address_space(3))) unsigned int*)l, 16, 0, 0);
}
__device__ __forceinline__ void gload16b(const __hip_bfloat16* g, __hip_bfloat16* l) {
    __builtin_amdgcn_global_load_lds(
        (const __attribute__((address_space(1))) unsigned int*)g,
        (__attribute__((address_space(3))) unsigned int*)l, 16, 0, 0);
}

// ---------------------------------------------------------------------------
// prep_all: blocks 0..4095 = data prep; 4096..4351 = W prep; 4352..6403 = W copy.
// data f32 -> Dh,Dl fp16 fragment-tiled [by(64)][ks(32)][tl(8)][lane(64)][8]
//   (row = by*256 + tl*32 + (ln&31), k = ks*16 + (ln>>5)*8 + j)
// W cols 1..512 -> Wh,Wl fp16 tiled [nb(8)][ks(32)][tm(4)][64][8].
// Split: a = ah + al/2048 (al pre-scaled by 2048 into fp16 normal range).
// ---------------------------------------------------------------------------
__global__ __launch_bounds__(256)
void prep_all(const float* __restrict__ data, const float* __restrict__ W,
              _Float16* __restrict__ Dh, _Float16* __restrict__ Dl,
              _Float16* __restrict__ Wh, _Float16* __restrict__ Wl,
              float* __restrict__ outW)
{
    if (blockIdx.x < 4096) {
        int idx = blockIdx.x * 256 + threadIdx.x;
        int b  = idx >> 6;
        int k8 = idx & 63;
        const float4 v0 = *reinterpret_cast<const float4*>(&data[(size_t)b * DDIM + k8 * 8]);
        const float4 v1 = *reinterpret_cast<const float4*>(&data[(size_t)b * DDIM + k8 * 8 + 4]);
        float a[8] = {v0.x, v0.y, v0.z, v0.w, v1.x, v1.y, v1.z, v1.w};
        __align__(16) _Float16 h[8], l[8];
#pragma unroll
        for (int j = 0; j < 8; ++j) {
            h[j] = (_Float16)a[j];
            l[j] = (_Float16)((a[j] - (float)h[j]) * 2048.f);
        }
        int by = b >> 8, tl = (b >> 5) & 7, ln = (b & 31) | ((k8 & 1) << 5), ks = k8 >> 1;
        size_t off = ((((size_t)by * 32 + ks) * 8 + tl) * 64 + ln) * 8;
        *reinterpret_cast<ulonglong2*>(&Dh[off]) = *reinterpret_cast<const ulonglong2*>(h);
        *reinterpret_cast<ulonglong2*>(&Dl[off]) = *reinterpret_cast<const ulonglong2*>(l);
    } else if (blockIdx.x < 4352) {
        int idx = (blockIdx.x - 4096) * 256 + threadIdx.x;
        int t  = idx & 255;
        int ks = (idx >> 8) & 31;
        int nb = idx >> 13;
        int tm = t >> 6, ln = t & 63;
        int node = nb * 128 + tm * 32 + (ln & 31);
        int k = ks * 16 + (ln >> 5) * 8;
        __align__(16) _Float16 h[8], l[8];
        if (node < NNODES) {
#pragma unroll
            for (int j = 0; j < 8; ++j) {
                float a = W[(size_t)node * 513 + 1 + k + j];
                h[j] = (_Float16)a;
                l[j] = (_Float16)((a - (float)h[j]) * 2048.f);
            }
        } else {
#pragma unroll
            for (int j = 0; j < 8; ++j) { h[j] = (_Float16)0.f; l[j] = (_Float16)0.f; }
        }
        size_t off = (size_t)idx * 8;
        *reinterpret_cast<ulonglong2*>(&Wh[off]) = *reinterpret_cast<const ulonglong2*>(h);
        *reinterpret_cast<ulonglong2*>(&Wl[off]) = *reinterpret_cast<const ulonglong2*>(l);
    } else {
        int i = (blockIdx.x - 4352) * 256 + threadIdx.x;
        if (i < NNODES * 513) outW[i] = W[i];
    }
}

// ---------------------------------------------------------------------------
// GEMM1 fp16-split MFMA. Tile 128 nodes x 256 batch, 8 waves (2x4), BK=32.
// Single-barrier pipeline: STAGE(next) at tile top, compute, vmcnt(0)+barrier
// at tile bottom (loads have whole tile to land -> no stall).
// ---------------------------------------------------------------------------
__global__ __launch_bounds__(512, 2)
void gemm1_mfma(const _Float16* __restrict__ Wh, const _Float16* __restrict__ Wl,
                const _Float16* __restrict__ Dh, const _Float16* __restrict__ Dl,
                const float* __restrict__ W, const float* __restrict__ beta,
                float* __restrict__ PT)
{
    __shared__ _Float16 lds[2][24576];   // 2 x 48KB: [Wh 4K][Wl 4K][Dh 8K][Dl 8K] elems
    const int tid = threadIdx.x;          // 0..511
    const int lane = tid & 63;
    const int wv = tid >> 6;              // 0..7
    const int wm = wv & 1, wn = wv >> 1;  // wn 0..3
    const int id = blockIdx.x;
    const int xcd = id & 7, slot = id >> 3;
    const int bx = slot & 7;              // node block (128)
    const int by = xcd * 8 + (slot >> 3); // batch block (256)
    const size_t wofs = (size_t)bx * 65536 + tid * 8;
    const size_t dofs = (size_t)by * 131072 + tid * 8;

    f32x16v acc_h[2][2] = {};
    f32x16v acc_l[2][2] = {};

#define STAGE(buf, tt) do { \
        const size_t wo = wofs + (size_t)(tt) * 4096; \
        const size_t dd = dofs + (size_t)(tt) * 8192; \
        gload16h(Wh + wo,        &lds[buf][tid * 8]); \
        gload16h(Wl + wo,        &lds[buf][4096  + tid * 8]); \
        gload16h(Dh + dd,        &lds[buf][8192  + tid * 8]); \
        gload16h(Dh + dd + 4096, &lds[buf][12288 + tid * 8]); \
        gload16h(Dl + dd,        &lds[buf][16384 + tid * 8]); \
        gload16h(Dl + dd + 4096, &lds[buf][20480 + tid * 8]); \
    } while (0)

    // prologue
    STAGE(0, 0);
    asm volatile("s_waitcnt vmcnt(0)" ::: "memory");
    __builtin_amdgcn_s_barrier();

    for (int t = 0; t < 16; ++t) {
        const int cur = t & 1;
        if (t < 15) STAGE(cur ^ 1, t + 1);
        const _Float16* L = lds[cur];
#pragma unroll
        for (int kcl = 0; kcl < 2; ++kcl) {
            f16x8 ah[2], al[2], bh[2], bl[2];
#pragma unroll
            for (int i = 0; i < 2; ++i) {
                int ao = ((kcl * 4 + wm * 2 + i) * 64 + lane) * 8;
                ah[i] = *reinterpret_cast<const f16x8*>(&L[ao]);
                al[i] = *reinterpret_cast<const f16x8*>(&L[4096 + ao]);
            }
#pragma unroll
            for (int j = 0; j < 2; ++j) {
                int bo = ((kcl * 8 + wn * 2 + j) * 64 + lane) * 8;
                bh[j] = *reinterpret_cast<const f16x8*>(&L[8192 + bo]);
                bl[j] = *reinterpret_cast<const f16x8*>(&L[16384 + bo]);
            }
            __builtin_amdgcn_s_setprio(1);
#pragma unroll
            for (int i = 0; i < 2; ++i)
#pragma unroll
                for (int j = 0; j < 2; ++j) {
                    acc_h[i][j] = __builtin_amdgcn_mfma_f32_32x32x16_f16(ah[i], bh[j], acc_h[i][j], 0, 0, 0);
                    acc_l[i][j] = __builtin_amdgcn_mfma_f32_32x32x16_f16(ah[i], bl[j], acc_l[i][j], 0, 0, 0);
                    acc_l[i][j] = __builtin_amdgcn_mfma_f32_32x32x16_f16(al[i], bh[j], acc_l[i][j], 0, 0, 0);
                }
            __builtin_amdgcn_s_setprio(0);
        }
        if (t < 15) asm volatile("s_waitcnt vmcnt(0)" ::: "memory");
        __builtin_amdgcn_s_barrier();
    }
#undef STAGE

    // epilogue: z -> sigmoid -> PT[node][batch]
#pragma unroll
    for (int i = 0; i < 2; ++i) {
#pragma unroll
        for (int r = 0; r < 16; ++r) {
            int node = bx * 128 + wm * 64 + i * 32 + ((r & 3) + 8 * (r >> 2) + 4 * (lane >> 5));
            if (node < NNODES) {
                float w0 = W[(size_t)node * 513];
                float bt = beta[node];
#pragma unroll
                for (int j = 0; j < 2; ++j) {
                    float z = acc_h[i][j][r] + acc_l[i][j][r] * 4.8828125e-4f;
                    float s = bt * (z + w0);
                    float p = 1.f / (1.f + expf(-s));
                    PT[(size_t)node * B_ROWS + by * 256 + wn * 64 + j * 32 + (lane & 31)] = p;
                }
            }
        }
    }
}

// ---------------------------------------------------------------------------
// Tree pass: thread = row, one subtree-pair per block, fragment-tiled MU2 out.
// MU2 layout [mb(128)][kc(64)][mt(4)][lane(64)][8]:
//   row = mb*128+mt*32+(ln&31), leaf = kc*16+(ln>>5)*8+j
// ---------------------------------------------------------------------------
__global__ __launch_bounds__(256, 4)
void tree_pass(const float* __restrict__ PT,
               __hip_bfloat16* __restrict__ MU2,
               float* __restrict__ pval,          // [16][16384]
               int*   __restrict__ pidx)          // [16][16384]
{
    const int tid = threadIdx.x;
    const int rb = blockIdx.x & 63;
    const int g  = blockIdx.x >> 6;        // pair 0..15
    const int b  = rb * 256 + tid;

    const int c4 = 15 + g;
    const int n3 = (c4 - 1) >> 1;
    const int n2 = (n3 - 1) >> 1;
    const int n1 = (n2 - 1) >> 1;
    const float pc4 = PT[(size_t)c4 * B_ROWS + b];
    const float pn3 = PT[(size_t)n3 * B_ROWS + b];
    const float pn2 = PT[(size_t)n2 * B_ROWS + b];
    const float pn1 = PT[(size_t)n1 * B_ROWS + b];
    const float pn0 = PT[b];
    float pre = ((c4 & 1) ? pn3 : 1.f - pn3)
              * ((n3 & 1) ? pn2 : 1.f - pn2)
              * ((n2 & 1) ? pn1 : 1.f - pn1)
              * ((n1 & 1) ? pn0 : 1.f - pn0);
    float root[2] = { pre * pc4, pre * (1.f - pc4) };

    __align__(16) __hip_bfloat16 mbv[64];
    float bestv = -1.f; int besti = 0;
#pragma unroll
    for (int ss = 0; ss < 2; ++ss) {
        const int t = 2 * g + ss;
        float s[32];
#pragma unroll
        for (int u = 1; u < 32; ++u) {
            int lvl = 31 - __clz(u);
            int node = ((32 << lvl) - 1) + t * (1 << lvl) + (u - (1 << lvl));
            s[u] = PT[(size_t)node * B_ROWS + b];
        }
        float w[64];
        w[1] = root[ss];
#pragma unroll
        for (int u = 1; u < 32; ++u) {
            w[2 * u]     = w[u] * s[u];
            w[2 * u + 1] = w[u] * (1.f - s[u]);
        }
#pragma unroll
        for (int q = 0; q < 32; ++q) {
            float lv = w[32 + q];
            mbv[ss * 32 + q] = __float2bfloat16(lv);
            if (lv > bestv) { bestv = lv; besti = t * 32 + q; }
        }
    }
    // scatter into fragment-tiled MU2: 8x 16B coalesced stores
    {
        const int mb_ = b >> 7, mt_ = (b >> 5) & 3, lnlo = b & 31;
        const ulonglong2* src = reinterpret_cast<const ulonglong2*>(mbv);
#pragma unroll
        for (int c = 0; c < 4; ++c) {
            size_t base16 = (((size_t)mb_ * 64 + g * 4 + c) * 4 + mt_) * 64;
            *reinterpret_cast<ulonglong2*>(&MU2[(base16 + lnlo) * 8])      = src[c * 2];
            *reinterpret_cast<ulonglong2*>(&MU2[(base16 + 32 + lnlo) * 8]) = src[c * 2 + 1];
        }
    }
    pval[(size_t)g * B_ROWS + b] = bestv;
    pidx[(size_t)g * B_ROWS + b] = besti;
}

// ---------------------------------------------------------------------------
// colsum on MU2: grid 256 = kc(64) x mbg(4); block reduces 16 leaves over
// 4096 rows -> partial[mbg][1024]. No atomics.
// ---------------------------------------------------------------------------
__global__ __launch_bounds__(256)
void colsum(const __hip_bfloat16* __restrict__ MU2, float* __restrict__ partial)
{
    __shared__ float red[4][2][8];
    const int blk = blockIdx.x;
    const int kc = blk >> 2, mbg = blk & 3;
    const int t = threadIdx.x;
    const int w = t >> 6, ln = t & 63;
    float a[8] = {0.f, 0.f, 0.f, 0.f, 0.f, 0.f, 0.f, 0.f};
    for (int it = 0; it < 32; ++it) {
        int it2 = it * 4 + w;
        int mb = mbg * 32 + (it2 >> 2), mt = it2 & 3;
        size_t a16 = (((size_t)mb * 64 + kc) * 4 + mt) * 64 + ln;
        ulonglong2 u = *reinterpret_cast<const ulonglong2*>(&MU2[a16 * 8]);
        const unsigned short* hs = reinterpret_cast<const unsigned short*>(&u);
#pragma unroll
        for (int j = 0; j < 8; ++j) a[j] += bf2f(hs[j]);
    }
#pragma unroll
    for (int m = 1; m < 32; m <<= 1)
#pragma unroll
        for (int j = 0; j < 8; ++j) a[j] += __shfl_xor(a[j], m, 64);
    if ((ln & 31) == 0) {
#pragma unroll
        for (int j = 0; j < 8; ++j) red[w][ln >> 5][j] = a[j];
    }
    __syncthreads();
    if (t < 16) {
        float s = red[0][t >> 3][t & 7] + red[1][t >> 3][t & 7]
                + red[2][t >> 3][t & 7] + red[3][t >> 3][t & 7];
        partial[(size_t)mbg * NLEAF + kc * 16 + t] = s;
    }
}

// ---------------------------------------------------------------------------
// softmax over param rows -> logdist (f32) + DT2 (bf16 fragment-tiled
// [kc(64)][nt(8)][lane(64)][8]: col=nt*32+(ln&31), leaf=kc*16+(ln>>5)*8+j)
// ---------------------------------------------------------------------------
__global__ __launch_bounds__(256)
void softmax_param(const float* __restrict__ param,
                   float* __restrict__ logdist,
                   __hip_bfloat16* __restrict__ DT2)
{
    __shared__ float red[4], red2[4];
    int l = blockIdx.x;
    int o = threadIdx.x;
    float x = param[(size_t)l * ODIM + o];
    float m = x;
#pragma unroll
    for (int s = 1; s < 64; s <<= 1) m = fmaxf(m, __shfl_xor(m, s, 64));
    if ((o & 63) == 0) red[o >> 6] = m;
    __syncthreads();
    m = fmaxf(fmaxf(red[0], red[1]), fmaxf(red[2], red[3]));
    float e = expf(x - m);
    float s = e;
#pragma unroll
    for (int k = 1; k < 64; k <<= 1) s += __shfl_xor(s, k, 64);
    if ((o & 63) == 0) red2[o >> 6] = s;
    __syncthreads();
    s = red2[0] + red2[1] + red2[2] + red2[3];
    float d = e / s;
    logdist[(size_t)l * ODIM + o] = logf(d);
    int kc = l >> 4, kk = l & 15;
    int lane = (o & 31) | ((kk >> 3) << 5);
    DT2[(((size_t)kc * 8 + (o >> 5)) * 64 + lane) * 8 + (kk & 7)] = __float2bfloat16(d);
}

// ---------------------------------------------------------------------------
// penalty: reduce 4 partials, heap-aggregate, sum log terms.
// ---------------------------------------------------------------------------
__global__ __launch_bounds__(256)
void penalty_kernel(const float* __restrict__ partial, float* __restrict__ out_pen)
{
    __shared__ float M[2048];
    __shared__ double dred[256];
    int tid = threadIdx.x;
    for (int i = tid; i < 1024; i += 256)
        M[1024 + i] = partial[i] + partial[NLEAF + i] + partial[2 * NLEAF + i] + partial[3 * NLEAF + i];
    __syncthreads();
    for (int n = 512; n >= 1; n >>= 1) {
        for (int u = n + tid; u < 2 * n; u += 256) M[u] = M[2 * u] + M[2 * u + 1];
        __syncthreads();
    }
    double acc = 0.0;
    for (int u = 2 + tid; u < 2048; u += 256) {
        int lvl = 31 - __clz(u);
        float a = M[u] / (M[u >> 1] + EPSV);
        a = fminf(fmaxf(a, EPSV), 1.f - EPSV);
        float term = logf(a) + logf(1.f - a);
        acc -= ldexp((double)LAMDA * 0.5, 1 - lvl) * (double)term;
    }
    dred[tid] = acc;
    __syncthreads();
    for (int s = 128; s > 0; s >>= 1) {
        if (tid < s) dred[tid] += dred[tid + s];
        __syncthreads();
    }
    if (tid == 0) out_pen[0] = (float)dred[0];
}

// ---------------------------------------------------------------------------
// GEMM2: out1 = log(MU2 @ DT2), M-tile 64, N=256, BK=32, dbuf gload_lds.
// grid 256, 4 waves; wave w covers cols w*64..w*64+63 (Mf=2,Nf=2).
// ---------------------------------------------------------------------------
__global__ __launch_bounds__(256)
void gemm2_log(const __hip_bfloat16* __restrict__ MU2,
               const __hip_bfloat16* __restrict__ DT2,
               float* __restrict__ out1)
{
    __shared__ __hip_bfloat16 ldsA[2][2048];   // 2 x 4KB
    __shared__ __hip_bfloat16 ldsB[2][8192];   // 2 x 16KB (two kc slices)
    const int tid = threadIdx.x;
    const int lane = tid & 63;
    const int w = tid >> 6;
    const int blk = blockIdx.x;
    const int m0 = blk * 64;
    const int mb = blk >> 1;
    const int mtbase = (blk & 1) * 2;
    const int s_kcl = tid >> 7, s_mti = (tid >> 6) & 1, s_ln = tid & 63;

    f32x16v acc[2][2] = {};

#define STAGE2(buf, kc0) do { \
        size_t sa16 = (((size_t)mb * 64 + (kc0) + s_kcl) * 4 + mtbase + s_mti) * 64 + s_ln; \
        gload16b(MU2 + sa16 * 8, &ldsA[buf][tid * 8]); \
        gload16b(DT2 + ((size_t)(kc0) * 512 + tid) * 8,             &ldsB[buf][tid * 8]); \
        gload16b(DT2 + ((size_t)(kc0) * 512 + 256 + tid) * 8,       &ldsB[buf][2048 + tid * 8]); \
        gload16b(DT2 + ((size_t)((kc0) + 1) * 512 + tid) * 8,       &ldsB[buf][4096 + tid * 8]); \
        gload16b(DT2 + ((size_t)((kc0) + 1) * 512 + 256 + tid) * 8, &ldsB[buf][6144 + tid * 8]); \
    } while (0)

    STAGE2(0, 0);
    for (int it = 0; it < 32; ++it) {
        const int cur = it & 1;
        if (it + 1 < 32) {
            STAGE2(cur ^ 1, 2 * (it + 1));
            asm volatile("s_waitcnt vmcnt(5)" ::: "memory");
        } else {
            asm volatile("s_waitcnt vmcnt(0)" ::: "memory");
        }
        __builtin_amdgcn_s_barrier();
        bf16x8v a[2][2], bb[2][2];
#pragma unroll
        for (int kcl = 0; kcl < 2; ++kcl)
#pragma unroll
            for (int i = 0; i < 2; ++i) {
                a[kcl][i]  = *reinterpret_cast<const bf16x8v*>(&ldsA[cur][((kcl * 2 + i) * 64 + lane) * 8]);
                bb[kcl][i] = *reinterpret_cast<const bf16x8v*>(&ldsB[cur][((kcl * 8 + 2 * w + i) * 64 + lane) * 8]);
            }
        __builtin_amdgcn_s_setprio(1);
#pragma unroll
        for (int kcl = 0; kcl < 2; ++kcl)
#pragma unroll
            for (int i = 0; i < 2; ++i)
#pragma unroll
                for (int j = 0; j < 2; ++j)
                    acc[i][j] = __builtin_amdgcn_mfma_f32_32x32x16_bf16(a[kcl][i], bb[kcl][j], acc[i][j], 0, 0, 0);
        __builtin_amdgcn_s_setprio(0);
        asm volatile("s_waitcnt lgkmcnt(0)" ::: "memory");
        __builtin_amdgcn_s_barrier();
    }
#undef STAGE2
#pragma unroll
    for (int i = 0; i < 2; ++i)
#pragma unroll
        for (int j = 0; j < 2; ++j)
#pragma unroll
            for (int r = 0; r < 16; ++r) {
                int row = m0 + i * 32 + (r & 3) + 8 * (r >> 2) + 4 * (lane >> 5);
                int col = w * 64 + j * 32 + (lane & 31);
                out1[(size_t)row * ODIM + col] = logf(acc[i][j][r]);
            }
}

// ---------------------------------------------------------------------------
// fused argmax over 16 partials + gather of logdist rows.
// ---------------------------------------------------------------------------
__global__ __launch_bounds__(256)
void argmax_gather(const float* __restrict__ pval, const int* __restrict__ pidx,
                   const float* __restrict__ logdist, float* __restrict__ out0)
{
    __shared__ int sid[64];
    const int blk = blockIdx.x;      // 256 blocks x 64 rows
    const int t = threadIdx.x;
    if (t < 64) {
        int row = blk * 64 + t;
        float bv = -1.f; int bi = 0;
        for (int g = 0; g < 16; ++g) {
            float v = pval[(size_t)g * B_ROWS + row];
            if (v > bv) { bv = v; bi = pidx[(size_t)g * B_ROWS + row]; }
        }
        sid[t] = bi;
    }
    __syncthreads();
    for (int rr = 0; rr < 64; ++rr) {
        int id = sid[rr];
        out0[(size_t)(blk * 64 + rr) * ODIM + t] = logdist[(size_t)id * ODIM + t];
    }
}

// ---------------------------------------------------------------------------
extern "C" void kernel_launch(void* const* d_in, const int* in_sizes, int n_in,
                              void* d_out, int out_size, void* d_ws, size_t ws_size,
                              hipStream_t stream)
{
    (void)in_sizes; (void)n_in; (void)out_size; (void)ws_size;
    const float* data  = (const float*)d_in[0];
    const float* W     = (const float*)d_in[1];
    const float* beta  = (const float*)d_in[2];
    const float* param = (const float*)d_in[3];
    float* out = (float*)d_out;

    char* ws = (char*)d_ws;
    size_t off = 0;
    float* PT = (float*)(ws + off);                   off += (size_t)NNODES * B_ROWS * 4;   // 67.04 MB
    char* X = ws + off;                               off += 2 * 1048576 + 2 * 16777216;    // 35.65 MB
    _Float16* Wh = (_Float16*)(X);
    _Float16* Wl = (_Float16*)(X + 1048576);
    _Float16* Dh = (_Float16*)(X + 2 * 1048576);
    _Float16* Dl = (_Float16*)(X + 2 * 1048576 + 16777216);
    __hip_bfloat16* MU2 = (__hip_bfloat16*)(X + 2 * 1048576);  // overlays Dh+Dl (33.55 MB)
    __hip_bfloat16* DT2 = (__hip_bfloat16*)(ws + off); off += (size_t)ODIM * NLEAF * 2;
    float* logdist = (float*)(ws + off);              off += (size_t)NLEAF * ODIM * 4;
    float* partial = (float*)(ws + off);              off += (size_t)4 * NLEAF * 4;
    float* pval    = (float*)(ws + off);              off += (size_t)16 * B_ROWS * 4;
    int*   pidx    = (int*)(ws + off);                off += (size_t)16 * B_ROWS * 4;

    float* out_logpred = out;
    float* out_logout  = out + (size_t)B_ROWS * ODIM;
    float* out_pen     = out + 2 * (size_t)B_ROWS * ODIM;
    float* out_W       = out_pen + 1;

    prep_all<<<6404, 256, 0, stream>>>(data, W, Dh, Dl, Wh, Wl, out_W);
    softmax_param<<<NLEAF, 256, 0, stream>>>(param, logdist, DT2);

    gemm1_mfma<<<512, 512, 0, stream>>>(Wh, Wl, Dh, Dl, W, beta, PT);

    tree_pass<<<1024, 256, 0, stream>>>(PT, MU2, pval, pidx);
    colsum<<<256, 256, 0, stream>>>(MU2, partial);
    penalty_kernel<<<1, 256, 0, stream>>>(partial, out_pen);

    gemm2_log<<<B_ROWS / 64, 256, 0, stream>>>(MU2, DT2, out_logout);
    argmax_gather<<<B_ROWS / 64, 256, 0, stream>>>(pval, pidx, logdist, out_logpred);
}

// Round 9
// 151.264 us; speedup vs baseline: 1.1508x; 1.0707x over previous
//
#include <hip/hip_runtime.h>
#include <hip/hip_bf16.h>

#define B_ROWS 16384
#define DDIM   512
#define NNODES 1023
#define NLEAF  1024
#define ODIM   256
#define LAMDA  1e-3
#define EPSV   1e-7f

typedef __bf16 bf16x8v __attribute__((ext_vector_type(8)));
typedef _Float16 f16x8 __attribute__((ext_vector_type(8)));
typedef float  f32x16v __attribute__((ext_vector_type(16)));

__device__ __forceinline__ float bf2f(unsigned short u) {
    return __uint_as_float(((unsigned)u) << 16);
}

// async global->LDS 16B copy (dst linear: wave-uniform base + lane*16)
__device__ __forceinline__ void gload16h(const _Float16* g, _Float16* l) {
    __builtin_amdgcn_global_load_lds(
        (const __attribute__((address_space(1))) unsigned int*)g,
        (__attribute__((address_space(3))) unsigned int*)l, 16, 0, 0);
}
__device__ __forceinline__ void gload16b(const __hip_bfloat16* g, __hip_bfloat16* l) {
    __builtin_amdgcn_global_load_lds(
        (const __attribute__((address_space(1))) unsigned int*)g,
        (__attribute__((address_space(3))) unsigned int*)l, 16, 0, 0);
}

// ---------------------------------------------------------------------------
// prep_all: blocks 0..4095 data prep; 4096..4351 W prep; 4352..6403 W copy;
// 6404..7427 softmax_param.
// data f32 -> Dh,Dl fp16 fragment-tiled [by(64)][ks(32)][tl(8)][lane(64)][8]
// W cols 1..512 -> Wh,Wl fp16 tiled [nb(8)][ks(32)][tm(4)][64][8].
// Split: a = ah + al/2048 (al pre-scaled by 2048 into fp16 normal range).
// softmax: param rows -> logdist (f32) + DT2 (bf16 fragment-tiled).
// ---------------------------------------------------------------------------
__global__ __launch_bounds__(256)
void prep_all(const float* __restrict__ data, const float* __restrict__ W,
              const float* __restrict__ param,
              _Float16* __restrict__ Dh, _Float16* __restrict__ Dl,
              _Float16* __restrict__ Wh, _Float16* __restrict__ Wl,
              float* __restrict__ outW,
              float* __restrict__ logdist, __hip_bfloat16* __restrict__ DT2)
{
    __shared__ float red[4], red2[4];
    if (blockIdx.x < 4096) {
        int idx = blockIdx.x * 256 + threadIdx.x;
        int b  = idx >> 6;
        int k8 = idx & 63;
        const float4 v0 = *reinterpret_cast<const float4*>(&data[(size_t)b * DDIM + k8 * 8]);
        const float4 v1 = *reinterpret_cast<const float4*>(&data[(size_t)b * DDIM + k8 * 8 + 4]);
        float a[8] = {v0.x, v0.y, v0.z, v0.w, v1.x, v1.y, v1.z, v1.w};
        __align__(16) _Float16 h[8], l[8];
#pragma unroll
        for (int j = 0; j < 8; ++j) {
            h[j] = (_Float16)a[j];
            l[j] = (_Float16)((a[j] - (float)h[j]) * 2048.f);
        }
        int by = b >> 8, tl = (b >> 5) & 7, ln = (b & 31) | ((k8 & 1) << 5), ks = k8 >> 1;
        size_t off = ((((size_t)by * 32 + ks) * 8 + tl) * 64 + ln) * 8;
        *reinterpret_cast<ulonglong2*>(&Dh[off]) = *reinterpret_cast<const ulonglong2*>(h);
        *reinterpret_cast<ulonglong2*>(&Dl[off]) = *reinterpret_cast<const ulonglong2*>(l);
    } else if (blockIdx.x < 4352) {
        int idx = (blockIdx.x - 4096) * 256 + threadIdx.x;
        int t  = idx & 255;
        int ks = (idx >> 8) & 31;
        int nb = idx >> 13;
        int tm = t >> 6, ln = t & 63;
        int node = nb * 128 + tm * 32 + (ln & 31);
        int k = ks * 16 + (ln >> 5) * 8;
        __align__(16) _Float16 h[8], l[8];
        if (node < NNODES) {
#pragma unroll
            for (int j = 0; j < 8; ++j) {
                float a = W[(size_t)node * 513 + 1 + k + j];
                h[j] = (_Float16)a;
                l[j] = (_Float16)((a - (float)h[j]) * 2048.f);
            }
        } else {
#pragma unroll
            for (int j = 0; j < 8; ++j) { h[j] = (_Float16)0.f; l[j] = (_Float16)0.f; }
        }
        size_t off = (size_t)idx * 8;
        *reinterpret_cast<ulonglong2*>(&Wh[off]) = *reinterpret_cast<const ulonglong2*>(h);
        *reinterpret_cast<ulonglong2*>(&Wl[off]) = *reinterpret_cast<const ulonglong2*>(l);
    } else if (blockIdx.x < 6404) {
        int i = (blockIdx.x - 4352) * 256 + threadIdx.x;
        if (i < NNODES * 513) outW[i] = W[i];
    } else {
        // softmax over param row l
        int l = blockIdx.x - 6404;
        int o = threadIdx.x;
        float x = param[(size_t)l * ODIM + o];
        float m = x;
#pragma unroll
        for (int s = 1; s < 64; s <<= 1) m = fmaxf(m, __shfl_xor(m, s, 64));
        if ((o & 63) == 0) red[o >> 6] = m;
        __syncthreads();
        m = fmaxf(fmaxf(red[0], red[1]), fmaxf(red[2], red[3]));
        float e = expf(x - m);
        float s = e;
#pragma unroll
        for (int k = 1; k < 64; k <<= 1) s += __shfl_xor(s, k, 64);
        if ((o & 63) == 0) red2[o >> 6] = s;
        __syncthreads();
        s = red2[0] + red2[1] + red2[2] + red2[3];
        float d = e / s;
        logdist[(size_t)l * ODIM + o] = logf(d);
        int kc = l >> 4, kk = l & 15;
        int lane = (o & 31) | ((kk >> 3) << 5);
        DT2[(((size_t)kc * 8 + (o >> 5)) * 64 + lane) * 8 + (kk & 7)] = __float2bfloat16(d);
    }
}

// ---------------------------------------------------------------------------
// GEMM1 fp16-split MFMA. Tile 128 nodes x 256 batch, 8 waves, BK=32.
// 8-phase-style schedule: 3 LDS buffers (144KB), 2-tile-deep prefetch,
// counted vmcnt(6) at tile boundary (never drains the pipe), 2 phases/tile:
//   { ds_read(kcl) || stage-issue ; barrier ; lgkmcnt(0) ; setprio1 12xMFMA
//     setprio0 ; [vmcnt] ; barrier }
// ---------------------------------------------------------------------------
__global__ __launch_bounds__(512, 2)
void gemm1_mfma(const _Float16* __restrict__ Wh, const _Float16* __restrict__ Wl,
                const _Float16* __restrict__ Dh, const _Float16* __restrict__ Dl,
                const float* __restrict__ W, const float* __restrict__ beta,
                float* __restrict__ PT)
{
    __shared__ _Float16 lds[3][24576];   // 3 x 48KB: [Wh 4K][Wl 4K][Dh 8K][Dl 8K]
    const int tid = threadIdx.x;          // 0..511
    const int lane = tid & 63;
    const int wv = tid >> 6;              // 0..7
    const int wm = wv & 1, wn = wv >> 1;  // wn 0..3
    const int id = blockIdx.x;
    const int xcd = id & 7, slot = id >> 3;
    const int bx = slot & 7;              // node block (128)
    const int by = xcd * 8 + (slot >> 3); // batch block (256)
    const size_t wofs = (size_t)bx * 65536 + tid * 8;
    const size_t dofs = (size_t)by * 131072 + tid * 8;

    f32x16v acc_h[2][2] = {};
    f32x16v acc_l[2][2] = {};

#define STAGE(buf, tt) do { \
        const size_t wo = wofs + (size_t)(tt) * 4096; \
        const size_t dd = dofs + (size_t)(tt) * 8192; \
        gload16h(Wh + wo,        &lds[buf][tid * 8]); \
        gload16h(Wl + wo,        &lds[buf][4096  + tid * 8]); \
        gload16h(Dh + dd,        &lds[buf][8192  + tid * 8]); \
        gload16h(Dh + dd + 4096, &lds[buf][12288 + tid * 8]); \
        gload16h(Dl + dd,        &lds[buf][16384 + tid * 8]); \
        gload16h(Dl + dd + 4096, &lds[buf][20480 + tid * 8]); \
    } while (0)

#define LOADFRAG(L, kcl) do { \
        _Pragma("unroll") \
        for (int i = 0; i < 2; ++i) { \
            int ao = (((kcl) * 4 + wm * 2 + i) * 64 + lane) * 8; \
            ah[i] = *reinterpret_cast<const f16x8*>(&(L)[ao]); \
            al[i] = *reinterpret_cast<const f16x8*>(&(L)[4096 + ao]); \
        } \
        _Pragma("unroll") \
        for (int j = 0; j < 2; ++j) { \
            int bo = (((kcl) * 8 + wn * 2 + j) * 64 + lane) * 8; \
            bh[j] = *reinterpret_cast<const f16x8*>(&(L)[8192 + bo]); \
            bl[j] = *reinterpret_cast<const f16x8*>(&(L)[16384 + bo]); \
        } \
    } while (0)

#define MFMA12() do { \
        _Pragma("unroll") \
        for (int i = 0; i < 2; ++i) \
        _Pragma("unroll") \
        for (int j = 0; j < 2; ++j) { \
            acc_h[i][j] = __builtin_amdgcn_mfma_f32_32x32x16_f16(ah[i], bh[j], acc_h[i][j], 0, 0, 0); \
            acc_l[i][j] = __builtin_amdgcn_mfma_f32_32x32x16_f16(ah[i], bl[j], acc_l[i][j], 0, 0, 0); \
            acc_l[i][j] = __builtin_amdgcn_mfma_f32_32x32x16_f16(al[i], bh[j], acc_l[i][j], 0, 0, 0); \
        } \
    } while (0)

    // prologue: 2-deep prefetch; wait for tile0's 6 loads (6 newer stay in flight)
    STAGE(0, 0);
    STAGE(1, 1);
    asm volatile("s_waitcnt vmcnt(6)" ::: "memory");
    __builtin_amdgcn_s_barrier();

    for (int t = 0; t < 16; ++t) {
        const _Float16* L = lds[t % 3];
        f16x8 ah[2], al[2], bh[2], bl[2];

        // ---- phase A (kcl=0): ds_read + stage-issue(t+2) ----
        LOADFRAG(L, 0);
        if (t + 2 < 16) STAGE((t + 2) % 3, t + 2);
        __builtin_amdgcn_s_barrier();
        asm volatile("s_waitcnt lgkmcnt(0)" ::: "memory");
        __builtin_amdgcn_s_setprio(1);
        MFMA12();
        __builtin_amdgcn_s_setprio(0);
        __builtin_amdgcn_s_barrier();

        // ---- phase B (kcl=1) ----
        LOADFRAG(L, 1);
        __builtin_amdgcn_s_barrier();
        asm volatile("s_waitcnt lgkmcnt(0)" ::: "memory");
        __builtin_amdgcn_s_setprio(1);
        MFMA12();
        __builtin_amdgcn_s_setprio(0);
        // counted drain: t+1's 6 loads must complete; t+2's 6 stay in flight
        if (t < 14) asm volatile("s_waitcnt vmcnt(6)" ::: "memory");
        else        asm volatile("s_waitcnt vmcnt(0)" ::: "memory");
        __builtin_amdgcn_s_barrier();
    }
#undef STAGE
#undef LOADFRAG
#undef MFMA12

    // epilogue: z -> sigmoid -> PT[node][batch]
#pragma unroll
    for (int i = 0; i < 2; ++i) {
#pragma unroll
        for (int r = 0; r < 16; ++r) {
            int node = bx * 128 + wm * 64 + i * 32 + ((r & 3) + 8 * (r >> 2) + 4 * (lane >> 5));
            if (node < NNODES) {
                float w0 = W[(size_t)node * 513];
                float bt = beta[node];
#pragma unroll
                for (int j = 0; j < 2; ++j) {
                    float z = acc_h[i][j][r] + acc_l[i][j][r] * 4.8828125e-4f;
                    float s = bt * (z + w0);
                    float p = 1.f / (1.f + expf(-s));
                    PT[(size_t)node * B_ROWS + by * 256 + wn * 64 + j * 32 + (lane & 31)] = p;
                }
            }
        }
    }
}

// ---------------------------------------------------------------------------
// Tree pass: thread = row, one subtree-pair per block, fragment-tiled MU2 out.
// MU2 layout [mb(128)][kc(64)][mt(4)][lane(64)][8]:
//   row = mb*128+mt*32+(ln&31), leaf = kc*16+(ln>>5)*8+j
// ---------------------------------------------------------------------------
__global__ __launch_bounds__(256, 4)
void tree_pass(const float* __restrict__ PT,
               __hip_bfloat16* __restrict__ MU2,
               float* __restrict__ pval,          // [16][16384]
               int*   __restrict__ pidx)          // [16][16384]
{
    const int tid = threadIdx.x;
    const int rb = blockIdx.x & 63;
    const int g  = blockIdx.x >> 6;        // pair 0..15
    const int b  = rb * 256 + tid;

    const int c4 = 15 + g;
    const int n3 = (c4 - 1) >> 1;
    const int n2 = (n3 - 1) >> 1;
    const int n1 = (n2 - 1) >> 1;
    const float pc4 = PT[(size_t)c4 * B_ROWS + b];
    const float pn3 = PT[(size_t)n3 * B_ROWS + b];
    const float pn2 = PT[(size_t)n2 * B_ROWS + b];
    const float pn1 = PT[(size_t)n1 * B_ROWS + b];
    const float pn0 = PT[b];
    float pre = ((c4 & 1) ? pn3 : 1.f - pn3)
              * ((n3 & 1) ? pn2 : 1.f - pn2)
              * ((n2 & 1) ? pn1 : 1.f - pn1)
              * ((n1 & 1) ? pn0 : 1.f - pn0);
    float root[2] = { pre * pc4, pre * (1.f - pc4) };

    __align__(16) __hip_bfloat16 mbv[64];
    float bestv = -1.f; int besti = 0;
#pragma unroll
    for (int ss = 0; ss < 2; ++ss) {
        const int t = 2 * g + ss;
        float s[32];
#pragma unroll
        for (int u = 1; u < 32; ++u) {
            int lvl = 31 - __clz(u);
            int node = ((32 << lvl) - 1) + t * (1 << lvl) + (u - (1 << lvl));
            s[u] = PT[(size_t)node * B_ROWS + b];
        }
        float w[64];
        w[1] = root[ss];
#pragma unroll
        for (int u = 1; u < 32; ++u) {
            w[2 * u]     = w[u] * s[u];
            w[2 * u + 1] = w[u] * (1.f - s[u]);
        }
#pragma unroll
        for (int q = 0; q < 32; ++q) {
            float lv = w[32 + q];
            mbv[ss * 32 + q] = __float2bfloat16(lv);
            if (lv > bestv) { bestv = lv; besti = t * 32 + q; }
        }
    }
    // scatter into fragment-tiled MU2: 8x 16B coalesced stores
    {
        const int mb_ = b >> 7, mt_ = (b >> 5) & 3, lnlo = b & 31;
        const ulonglong2* src = reinterpret_cast<const ulonglong2*>(mbv);
#pragma unroll
        for (int c = 0; c < 4; ++c) {
            size_t base16 = (((size_t)mb_ * 64 + g * 4 + c) * 4 + mt_) * 64;
            *reinterpret_cast<ulonglong2*>(&MU2[(base16 + lnlo) * 8])      = src[c * 2];
            *reinterpret_cast<ulonglong2*>(&MU2[(base16 + 32 + lnlo) * 8]) = src[c * 2 + 1];
        }
    }
    pval[(size_t)g * B_ROWS + b] = bestv;
    pidx[(size_t)g * B_ROWS + b] = besti;
}

// ---------------------------------------------------------------------------
// colsum (blocks 0..255) + argmax_gather (blocks 256..511).
// ---------------------------------------------------------------------------
__global__ __launch_bounds__(256)
void colsum_argmax(const __hip_bfloat16* __restrict__ MU2, float* __restrict__ partial,
                   const float* __restrict__ pval, const int* __restrict__ pidx,
                   const float* __restrict__ logdist, float* __restrict__ out0)
{
    __shared__ float red[4][2][8];
    __shared__ int sid[64];
    const int t = threadIdx.x;
    if (blockIdx.x < 256) {
        const int blk = blockIdx.x;
        const int kc = blk >> 2, mbg = blk & 3;
        const int w = t >> 6, ln = t & 63;
        float a[8] = {0.f, 0.f, 0.f, 0.f, 0.f, 0.f, 0.f, 0.f};
        for (int it = 0; it < 32; ++it) {
            int it2 = it * 4 + w;
            int mb = mbg * 32 + (it2 >> 2), mt = it2 & 3;
            size_t a16 = (((size_t)mb * 64 + kc) * 4 + mt) * 64 + ln;
            ulonglong2 u = *reinterpret_cast<const ulonglong2*>(&MU2[a16 * 8]);
            const unsigned short* hs = reinterpret_cast<const unsigned short*>(&u);
#pragma unroll
            for (int j = 0; j < 8; ++j) a[j] += bf2f(hs[j]);
        }
#pragma unroll
        for (int m = 1; m < 32; m <<= 1)
#pragma unroll
            for (int j = 0; j < 8; ++j) a[j] += __shfl_xor(a[j], m, 64);
        if ((ln & 31) == 0) {
#pragma unroll
            for (int j = 0; j < 8; ++j) red[w][ln >> 5][j] = a[j];
        }
        __syncthreads();
        if (t < 16) {
            float s = red[0][t >> 3][t & 7] + red[1][t >> 3][t & 7]
                    + red[2][t >> 3][t & 7] + red[3][t >> 3][t & 7];
            partial[(size_t)mbg * NLEAF + kc * 16 + t] = s;
        }
    } else {
        const int blk = blockIdx.x - 256;   // 256 blocks x 64 rows
        if (t < 64) {
            int row = blk * 64 + t;
            float bv = -1.f; int bi = 0;
            for (int g = 0; g < 16; ++g) {
                float v = pval[(size_t)g * B_ROWS + row];
                if (v > bv) { bv = v; bi = pidx[(size_t)g * B_ROWS + row]; }
            }
            sid[t] = bi;
        }
        __syncthreads();
        for (int rr = 0; rr < 64; ++rr) {
            int id = sid[rr];
            out0[(size_t)(blk * 64 + rr) * ODIM + t] = logdist[(size_t)id * ODIM + t];
        }
    }
}

// ---------------------------------------------------------------------------
// GEMM2 (blocks 0..255): out1 = log(MU2 @ DT2), M-tile 64, N=256, BK=32.
// Block 256: penalty (reduce partials, heap-aggregate, sum log terms).
// ---------------------------------------------------------------------------
__global__ __launch_bounds__(256)
void gemm2_penalty(const __hip_bfloat16* __restrict__ MU2,
                   const __hip_bfloat16* __restrict__ DT2,
                   float* __restrict__ out1,
                   const float* __restrict__ partial, float* __restrict__ out_pen)
{
    __shared__ __hip_bfloat16 ldsA[2][2048];   // 2 x 4KB
    __shared__ __hip_bfloat16 ldsB[2][8192];   // 2 x 16KB (two kc slices)
    __shared__ float M[2048];
    __shared__ double dred[256];
    const int tid = threadIdx.x;
    if (blockIdx.x == 256) {
        // ---- penalty ----
        for (int i = tid; i < 1024; i += 256)
            M[1024 + i] = partial[i] + partial[NLEAF + i] + partial[2 * NLEAF + i] + partial[3 * NLEAF + i];
        __syncthreads();
        for (int n = 512; n >= 1; n >>= 1) {
            for (int u = n + tid; u < 2 * n; u += 256) M[u] = M[2 * u] + M[2 * u + 1];
            __syncthreads();
        }
        double acc = 0.0;
        for (int u = 2 + tid; u < 2048; u += 256) {
            int lvl = 31 - __clz(u);
            float a = M[u] / (M[u >> 1] + EPSV);
            a = fminf(fmaxf(a, EPSV), 1.f - EPSV);
            float term = logf(a) + logf(1.f - a);
            acc -= ldexp((double)LAMDA * 0.5, 1 - lvl) * (double)term;
        }
        dred[tid] = acc;
        __syncthreads();
        for (int s = 128; s > 0; s >>= 1) {
            if (tid < s) dred[tid] += dred[tid + s];
            __syncthreads();
        }
        if (tid == 0) out_pen[0] = (float)dred[0];
        return;
    }
    const int lane = tid & 63;
    const int w = tid >> 6;
    const int blk = blockIdx.x;
    const int m0 = blk * 64;
    const int mb = blk >> 1;
    const int mtbase = (blk & 1) * 2;
    const int s_kcl = tid >> 7, s_mti = (tid >> 6) & 1, s_ln = tid & 63;

    f32x16v acc[2][2] = {};

#define STAGE2(buf, kc0) do { \
        size_t sa16 = (((size_t)mb * 64 + (kc0) + s_kcl) * 4 + mtbase + s_mti) * 64 + s_ln; \
        gload16b(MU2 + sa16 * 8, &ldsA[buf][tid * 8]); \
        gload16b(DT2 + ((size_t)(kc0) * 512 + tid) * 8,             &ldsB[buf][tid * 8]); \
        gload16b(DT2 + ((size_t)(kc0) * 512 + 256 + tid) * 8,       &ldsB[buf][2048 + tid * 8]); \
        gload16b(DT2 + ((size_t)((kc0) + 1) * 512 + tid) * 8,       &ldsB[buf][4096 + tid * 8]); \
        gload16b(DT2 + ((size_t)((kc0) + 1) * 512 + 256 + tid) * 8, &ldsB[buf][6144 + tid * 8]); \
    } while (0)

    STAGE2(0, 0);
    for (int it = 0; it < 32; ++it) {
        const int cur = it & 1;
        if (it + 1 < 32) {
            STAGE2(cur ^ 1, 2 * (it + 1));
            asm volatile("s_waitcnt vmcnt(5)" ::: "memory");
        } else {
            asm volatile("s_waitcnt vmcnt(0)" ::: "memory");
        }
        __builtin_amdgcn_s_barrier();
        bf16x8v a[2][2], bb[2][2];
#pragma unroll
        for (int kcl = 0; kcl < 2; ++kcl)
#pragma unroll
            for (int i = 0; i < 2; ++i) {
                a[kcl][i]  = *reinterpret_cast<const bf16x8v*>(&ldsA[cur][((kcl * 2 + i) * 64 + lane) * 8]);
                bb[kcl][i] = *reinterpret_cast<const bf16x8v*>(&ldsB[cur][((kcl * 8 + 2 * w + i) * 64 + lane) * 8]);
            }
        __builtin_amdgcn_s_setprio(1);
#pragma unroll
        for (int kcl = 0; kcl < 2; ++kcl)
#pragma unroll
            for (int i = 0; i < 2; ++i)
#pragma unroll
                for (int j = 0; j < 2; ++j)
                    acc[i][j] = __builtin_amdgcn_mfma_f32_32x32x16_bf16(a[kcl][i], bb[kcl][j], acc[i][j], 0, 0, 0);
        __builtin_amdgcn_s_setprio(0);
        asm volatile("s_waitcnt lgkmcnt(0)" ::: "memory");
        __builtin_amdgcn_s_barrier();
    }
#undef STAGE2
#pragma unroll
    for (int i = 0; i < 2; ++i)
#pragma unroll
        for (int j = 0; j < 2; ++j)
#pragma unroll
            for (int r = 0; r < 16; ++r) {
                int row = m0 + i * 32 + (r & 3) + 8 * (r >> 2) + 4 * (lane >> 5);
                int col = w * 64 + j * 32 + (lane & 31);
                out1[(size_t)row * ODIM + col] = logf(acc[i][j][r]);
            }
}

// ---------------------------------------------------------------------------
extern "C" void kernel_launch(void* const* d_in, const int* in_sizes, int n_in,
                              void* d_out, int out_size, void* d_ws, size_t ws_size,
                              hipStream_t stream)
{
    (void)in_sizes; (void)n_in; (void)out_size; (void)ws_size;
    const float* data  = (const float*)d_in[0];
    const float* W     = (const float*)d_in[1];
    const float* beta  = (const float*)d_in[2];
    const float* param = (const float*)d_in[3];
    float* out = (float*)d_out;

    char* ws = (char*)d_ws;
    size_t off = 0;
    float* PT = (float*)(ws + off);                   off += (size_t)NNODES * B_ROWS * 4;   // 67.04 MB
    char* X = ws + off;                               off += 2 * 1048576 + 2 * 16777216;    // 35.65 MB
    _Float16* Wh = (_Float16*)(X);
    _Float16* Wl = (_Float16*)(X + 1048576);
    _Float16* Dh = (_Float16*)(X + 2 * 1048576);
    _Float16* Dl = (_Float16*)(X + 2 * 1048576 + 16777216);
    __hip_bfloat16* MU2 = (__hip_bfloat16*)(X + 2 * 1048576);  // overlays Dh+Dl (33.55 MB)
    __hip_bfloat16* DT2 = (__hip_bfloat16*)(ws + off); off += (size_t)ODIM * NLEAF * 2;
    float* logdist = (float*)(ws + off);              off += (size_t)NLEAF * ODIM * 4;
    float* partial = (float*)(ws + off);              off += (size_t)4 * NLEAF * 4;
    float* pval    = (float*)(ws + off);              off += (size_t)16 * B_ROWS * 4;
    int*   pidx    = (int*)(ws + off);                off += (size_t)16 * B_ROWS * 4;

    float* out_logpred = out;
    float* out_logout  = out + (size_t)B_ROWS * ODIM;
    float* out_pen     = out + 2 * (size_t)B_ROWS * ODIM;
    float* out_W       = out_pen + 1;

    prep_all<<<7428, 256, 0, stream>>>(data, W, param, Dh, Dl, Wh, Wl, out_W, logdist, DT2);

    gemm1_mfma<<<512, 512, 0, stream>>>(Wh, Wl, Dh, Dl, W, beta, PT);

    tree_pass<<<1024, 256, 0, stream>>>(PT, MU2, pval, pidx);

    colsum_argmax<<<512, 256, 0, stream>>>(MU2, partial, pval, pidx, logdist, out_logpred);

    gemm2_penalty<<<257, 256, 0, stream>>>(MU2, DT2, out_logout, partial, out_pen);
}

// Round 10
// 151.031 us; speedup vs baseline: 1.1525x; 1.0015x over previous
//
#include <hip/hip_runtime.h>
#include <hip/hip_bf16.h>

#define B_ROWS 16384
#define DDIM   512
#define NNODES 1023
#define NLEAF  1024
#define ODIM   256
#define LAMDA  1e-3
#define EPSV   1e-7f

typedef __bf16 bf16x8v __attribute__((ext_vector_type(8)));
typedef _Float16 f16x8 __attribute__((ext_vector_type(8)));
typedef float  f32x16v __attribute__((ext_vector_type(16)));

__device__ __forceinline__ float bf2f(unsigned short u) {
    return __uint_as_float(((unsigned)u) << 16);
}

// async global->LDS 16B copy (dst linear: wave-uniform base + lane*16)
__device__ __forceinline__ void gload16h(const _Float16* g, _Float16* l) {
    __builtin_amdgcn_global_load_lds(
        (const __attribute__((address_space(1))) unsigned int*)g,
        (__attribute__((address_space(3))) unsigned int*)l, 16, 0, 0);
}
__device__ __forceinline__ void gload16b(const __hip_bfloat16* g, __hip_bfloat16* l) {
    __builtin_amdgcn_global_load_lds(
        (const __attribute__((address_space(1))) unsigned int*)g,
        (__attribute__((address_space(3))) unsigned int*)l, 16, 0, 0);
}

// ---------------------------------------------------------------------------
// prep_all: blocks 0..4095 data prep; 4096..4351 W prep; 4352..6403 W copy;
// 6404..7427 softmax_param.
// data f32 -> Dh,Dl fp16 fragment-tiled [by256(64)][ks(32)][tl(8)][lane(64)][8]
// W cols 1..512 -> Wh,Wl fp16 tiled [nb(8)][ks(32)][tm(4)][64][8].
// Split: a = ah + al/2048 (al pre-scaled by 2048 into fp16 normal range).
// ---------------------------------------------------------------------------
__global__ __launch_bounds__(256)
void prep_all(const float* __restrict__ data, const float* __restrict__ W,
              const float* __restrict__ param,
              _Float16* __restrict__ Dh, _Float16* __restrict__ Dl,
              _Float16* __restrict__ Wh, _Float16* __restrict__ Wl,
              float* __restrict__ outW,
              float* __restrict__ logdist, __hip_bfloat16* __restrict__ DT2)
{
    __shared__ float red[4], red2[4];
    if (blockIdx.x < 4096) {
        int idx = blockIdx.x * 256 + threadIdx.x;
        int b  = idx >> 6;
        int k8 = idx & 63;
        const float4 v0 = *reinterpret_cast<const float4*>(&data[(size_t)b * DDIM + k8 * 8]);
        const float4 v1 = *reinterpret_cast<const float4*>(&data[(size_t)b * DDIM + k8 * 8 + 4]);
        float a[8] = {v0.x, v0.y, v0.z, v0.w, v1.x, v1.y, v1.z, v1.w};
        __align__(16) _Float16 h[8], l[8];
#pragma unroll
        for (int j = 0; j < 8; ++j) {
            h[j] = (_Float16)a[j];
            l[j] = (_Float16)((a[j] - (float)h[j]) * 2048.f);
        }
        int by = b >> 8, tl = (b >> 5) & 7, ln = (b & 31) | ((k8 & 1) << 5), ks = k8 >> 1;
        size_t off = ((((size_t)by * 32 + ks) * 8 + tl) * 64 + ln) * 8;
        *reinterpret_cast<ulonglong2*>(&Dh[off]) = *reinterpret_cast<const ulonglong2*>(h);
        *reinterpret_cast<ulonglong2*>(&Dl[off]) = *reinterpret_cast<const ulonglong2*>(l);
    } else if (blockIdx.x < 4352) {
        int idx = (blockIdx.x - 4096) * 256 + threadIdx.x;
        int t  = idx & 255;
        int ks = (idx >> 8) & 31;
        int nb = idx >> 13;
        int tm = t >> 6, ln = t & 63;
        int node = nb * 128 + tm * 32 + (ln & 31);
        int k = ks * 16 + (ln >> 5) * 8;
        __align__(16) _Float16 h[8], l[8];
        if (node < NNODES) {
#pragma unroll
            for (int j = 0; j < 8; ++j) {
                float a = W[(size_t)node * 513 + 1 + k + j];
                h[j] = (_Float16)a;
                l[j] = (_Float16)((a - (float)h[j]) * 2048.f);
            }
        } else {
#pragma unroll
            for (int j = 0; j < 8; ++j) { h[j] = (_Float16)0.f; l[j] = (_Float16)0.f; }
        }
        size_t off = (size_t)idx * 8;
        *reinterpret_cast<ulonglong2*>(&Wh[off]) = *reinterpret_cast<const ulonglong2*>(h);
        *reinterpret_cast<ulonglong2*>(&Wl[off]) = *reinterpret_cast<const ulonglong2*>(l);
    } else if (blockIdx.x < 6404) {
        int i = (blockIdx.x - 4352) * 256 + threadIdx.x;
        if (i < NNODES * 513) outW[i] = W[i];
    } else {
        // softmax over param row l
        int l = blockIdx.x - 6404;
        int o = threadIdx.x;
        float x = param[(size_t)l * ODIM + o];
        float m = x;
#pragma unroll
        for (int s = 1; s < 64; s <<= 1) m = fmaxf(m, __shfl_xor(m, s, 64));
        if ((o & 63) == 0) red[o >> 6] = m;
        __syncthreads();
        m = fmaxf(fmaxf(red[0], red[1]), fmaxf(red[2], red[3]));
        float e = expf(x - m);
        float s = e;
#pragma unroll
        for (int k = 1; k < 64; k <<= 1) s += __shfl_xor(s, k, 64);
        if ((o & 63) == 0) red2[o >> 6] = s;
        __syncthreads();
        s = red2[0] + red2[1] + red2[2] + red2[3];
        float d = e / s;
        logdist[(size_t)l * ODIM + o] = logf(d);
        int kc = l >> 4, kk = l & 15;
        int lane = (o & 31) | ((kk >> 3) << 5);
        DT2[(((size_t)kc * 8 + (o >> 5)) * 64 + lane) * 8 + (kk & 7)] = __float2bfloat16(d);
    }
}

// ---------------------------------------------------------------------------
// GEMM1 fp16-split MFMA, occupancy-first config:
// tile 128 nodes x 128 batch, 8 waves (wm 0..1 x wn 0..3), per-wave out
// 64x32 -> acc 64 regs. BK=16, LDS 2x16KB dbuf -> 2 blocks/CU, 4 waves/SIMD.
// Per tile: 2 gloads/thread (counted vmcnt(2)), 6 ds_read_b128, 6 MFMA.
// ---------------------------------------------------------------------------
__global__ __launch_bounds__(512, 4)
void gemm1_mfma(const _Float16* __restrict__ Wh, const _Float16* __restrict__ Wl,
                const _Float16* __restrict__ Dh, const _Float16* __restrict__ Dl,
                const float* __restrict__ W, const float* __restrict__ beta,
                float* __restrict__ PT)
{
    __shared__ _Float16 lds[2][8192];   // 16KB/buf: [Wh 2048][Wl 2048][Dh 2048][Dl 2048]
    const int tid = threadIdx.x;          // 0..511
    const int lane = tid & 63;
    const int wv = tid >> 6;              // 0..7
    const int wm = wv & 1, wn = wv >> 1;  // node-half, batch-quarter
    const int id = blockIdx.x;
    const int xcd = id & 7, slot = id >> 3;
    const int bx = slot & 7;              // node block (128)
    const int by = xcd * 16 + (slot >> 3);// batch block (128), 0..127
    const int by256 = by >> 1;
    const int tlb = (by & 1) * 4;

    // staging source bases (per-lane global addresses; ks stride added in loop)
    const int q  = tid & 255;
    const int qt = q >> 6, qn = q & 63;
    const _Float16* Wsel = (tid < 256) ? Wh : Wl;
    const _Float16* Dsel = (tid < 256) ? Dh : Dl;
    const _Float16* wsrc = Wsel + (size_t)bx * 65536 + qt * 512 + qn * 8;       // +ks*2048
    const _Float16* dsrc = Dsel + (size_t)by256 * 131072 + (tlb + qt) * 512 + qn * 8; // +ks*4096

    f32x16v acc_h[2] = {};
    f32x16v acc_l[2] = {};

#define STAGE(buf, ks) do { \
        gload16h(wsrc + (size_t)(ks) * 2048, &lds[buf][tid * 8]); \
        gload16h(dsrc + (size_t)(ks) * 4096, &lds[buf][4096 + tid * 8]); \
    } while (0)

    STAGE(0, 0);
    for (int t = 0; t < 32; ++t) {
        const int cur = t & 1;
        if (t < 31) {
            STAGE(cur ^ 1, t + 1);
            asm volatile("s_waitcnt vmcnt(2)" ::: "memory");
        } else {
            asm volatile("s_waitcnt vmcnt(0)" ::: "memory");
        }
        __builtin_amdgcn_s_barrier();

        f16x8 ah[2], al[2], bh, bl;
#pragma unroll
        for (int i = 0; i < 2; ++i) {
            int ao = ((wm * 2 + i) * 64 + lane) * 8;
            ah[i] = *reinterpret_cast<const f16x8*>(&lds[cur][ao]);
            al[i] = *reinterpret_cast<const f16x8*>(&lds[cur][2048 + ao]);
        }
        {
            int bo = (wn * 64 + lane) * 8;
            bh = *reinterpret_cast<const f16x8*>(&lds[cur][4096 + bo]);
            bl = *reinterpret_cast<const f16x8*>(&lds[cur][6144 + bo]);
        }
        __builtin_amdgcn_s_setprio(1);
#pragma unroll
        for (int i = 0; i < 2; ++i) {
            acc_h[i] = __builtin_amdgcn_mfma_f32_32x32x16_f16(ah[i], bh, acc_h[i], 0, 0, 0);
            acc_l[i] = __builtin_amdgcn_mfma_f32_32x32x16_f16(ah[i], bl, acc_l[i], 0, 0, 0);
            acc_l[i] = __builtin_amdgcn_mfma_f32_32x32x16_f16(al[i], bh, acc_l[i], 0, 0, 0);
        }
        __builtin_amdgcn_s_setprio(0);
        asm volatile("s_waitcnt lgkmcnt(0)" ::: "memory");
        __builtin_amdgcn_s_barrier();
    }
#undef STAGE

    // epilogue: z -> sigmoid -> PT[node][batch]
#pragma unroll
    for (int i = 0; i < 2; ++i) {
#pragma unroll
        for (int r = 0; r < 16; ++r) {
            int node = bx * 128 + wm * 64 + i * 32 + ((r & 3) + 8 * (r >> 2) + 4 * (lane >> 5));
            if (node < NNODES) {
                float w0 = W[(size_t)node * 513];
                float bt = beta[node];
                float z = acc_h[i][r] + acc_l[i][r] * 4.8828125e-4f;
                float s = bt * (z + w0);
                float p = 1.f / (1.f + expf(-s));
                PT[(size_t)node * B_ROWS + by * 128 + wn * 32 + (lane & 31)] = p;
            }
        }
    }
}

// ---------------------------------------------------------------------------
// Tree pass: thread = row, one subtree-pair per block, fragment-tiled MU2 out.
// MU2 layout [mb(128)][kc(64)][mt(4)][lane(64)][8]:
//   row = mb*128+mt*32+(ln&31), leaf = kc*16+(ln>>5)*8+j
// ---------------------------------------------------------------------------
__global__ __launch_bounds__(256, 4)
void tree_pass(const float* __restrict__ PT,
               __hip_bfloat16* __restrict__ MU2,
               float* __restrict__ pval,          // [16][16384]
               int*   __restrict__ pidx)          // [16][16384]
{
    const int tid = threadIdx.x;
    const int rb = blockIdx.x & 63;
    const int g  = blockIdx.x >> 6;        // pair 0..15
    const int b  = rb * 256 + tid;

    const int c4 = 15 + g;
    const int n3 = (c4 - 1) >> 1;
    const int n2 = (n3 - 1) >> 1;
    const int n1 = (n2 - 1) >> 1;
    const float pc4 = PT[(size_t)c4 * B_ROWS + b];
    const float pn3 = PT[(size_t)n3 * B_ROWS + b];
    const float pn2 = PT[(size_t)n2 * B_ROWS + b];
    const float pn1 = PT[(size_t)n1 * B_ROWS + b];
    const float pn0 = PT[b];
    float pre = ((c4 & 1) ? pn3 : 1.f - pn3)
              * ((n3 & 1) ? pn2 : 1.f - pn2)
              * ((n2 & 1) ? pn1 : 1.f - pn1)
              * ((n1 & 1) ? pn0 : 1.f - pn0);
    float root[2] = { pre * pc4, pre * (1.f - pc4) };

    __align__(16) __hip_bfloat16 mbv[64];
    float bestv = -1.f; int besti = 0;
#pragma unroll
    for (int ss = 0; ss < 2; ++ss) {
        const int t = 2 * g + ss;
        float s[32];
#pragma unroll
        for (int u = 1; u < 32; ++u) {
            int lvl = 31 - __clz(u);
            int node = ((32 << lvl) - 1) + t * (1 << lvl) + (u - (1 << lvl));
            s[u] = PT[(size_t)node * B_ROWS + b];
        }
        float w[64];
        w[1] = root[ss];
#pragma unroll
        for (int u = 1; u < 32; ++u) {
            w[2 * u]     = w[u] * s[u];
            w[2 * u + 1] = w[u] * (1.f - s[u]);
        }
#pragma unroll
        for (int q = 0; q < 32; ++q) {
            float lv = w[32 + q];
            mbv[ss * 32 + q] = __float2bfloat16(lv);
            if (lv > bestv) { bestv = lv; besti = t * 32 + q; }
        }
    }
    // scatter into fragment-tiled MU2: 8x 16B coalesced stores
    {
        const int mb_ = b >> 7, mt_ = (b >> 5) & 3, lnlo = b & 31;
        const ulonglong2* src = reinterpret_cast<const ulonglong2*>(mbv);
#pragma unroll
        for (int c = 0; c < 4; ++c) {
            size_t base16 = (((size_t)mb_ * 64 + g * 4 + c) * 4 + mt_) * 64;
            *reinterpret_cast<ulonglong2*>(&MU2[(base16 + lnlo) * 8])      = src[c * 2];
            *reinterpret_cast<ulonglong2*>(&MU2[(base16 + 32 + lnlo) * 8]) = src[c * 2 + 1];
        }
    }
    pval[(size_t)g * B_ROWS + b] = bestv;
    pidx[(size_t)g * B_ROWS + b] = besti;
}

// ---------------------------------------------------------------------------
// colsum (blocks 0..255) + argmax_gather (blocks 256..511).
// ---------------------------------------------------------------------------
__global__ __launch_bounds__(256)
void colsum_argmax(const __hip_bfloat16* __restrict__ MU2, float* __restrict__ partial,
                   const float* __restrict__ pval, const int* __restrict__ pidx,
                   const float* __restrict__ logdist, float* __restrict__ out0)
{
    __shared__ float red[4][2][8];
    __shared__ int sid[64];
    const int t = threadIdx.x;
    if (blockIdx.x < 256) {
        const int blk = blockIdx.x;
        const int kc = blk >> 2, mbg = blk & 3;
        const int w = t >> 6, ln = t & 63;
        float a[8] = {0.f, 0.f, 0.f, 0.f, 0.f, 0.f, 0.f, 0.f};
        for (int it = 0; it < 32; ++it) {
            int it2 = it * 4 + w;
            int mb = mbg * 32 + (it2 >> 2), mt = it2 & 3;
            size_t a16 = (((size_t)mb * 64 + kc) * 4 + mt) * 64 + ln;
            ulonglong2 u = *reinterpret_cast<const ulonglong2*>(&MU2[a16 * 8]);
            const unsigned short* hs = reinterpret_cast<const unsigned short*>(&u);
#pragma unroll
            for (int j = 0; j < 8; ++j) a[j] += bf2f(hs[j]);
        }
#pragma unroll
        for (int m = 1; m < 32; m <<= 1)
#pragma unroll
            for (int j = 0; j < 8; ++j) a[j] += __shfl_xor(a[j], m, 64);
        if ((ln & 31) == 0) {
#pragma unroll
            for (int j = 0; j < 8; ++j) red[w][ln >> 5][j] = a[j];
        }
        __syncthreads();
        if (t < 16) {
            float s = red[0][t >> 3][t & 7] + red[1][t >> 3][t & 7]
                    + red[2][t >> 3][t & 7] + red[3][t >> 3][t & 7];
            partial[(size_t)mbg * NLEAF + kc * 16 + t] = s;
        }
    } else {
        const int blk = blockIdx.x - 256;   // 256 blocks x 64 rows
        if (t < 64) {
            int row = blk * 64 + t;
            float bv = -1.f; int bi = 0;
            for (int g = 0; g < 16; ++g) {
                float v = pval[(size_t)g * B_ROWS + row];
                if (v > bv) { bv = v; bi = pidx[(size_t)g * B_ROWS + row]; }
            }
            sid[t] = bi;
        }
        __syncthreads();
        for (int rr = 0; rr < 64; ++rr) {
            int id = sid[rr];
            out0[(size_t)(blk * 64 + rr) * ODIM + t] = logdist[(size_t)id * ODIM + t];
        }
    }
}

// ---------------------------------------------------------------------------
// GEMM2 (blocks 0..255): out1 = log(MU2 @ DT2), M-tile 64, N=256, BK=32.
// Block 256: penalty (reduce partials, heap-aggregate, sum log terms).
// ---------------------------------------------------------------------------
__global__ __launch_bounds__(256)
void gemm2_penalty(const __hip_bfloat16* __restrict__ MU2,
                   const __hip_bfloat16* __restrict__ DT2,
                   float* __restrict__ out1,
                   const float* __restrict__ partial, float* __restrict__ out_pen)
{
    __shared__ __hip_bfloat16 ldsA[2][2048];   // 2 x 4KB
    __shared__ __hip_bfloat16 ldsB[2][8192];   // 2 x 16KB (two kc slices)
    __shared__ float M[2048];
    __shared__ double dred[256];
    const int tid = threadIdx.x;
    if (blockIdx.x == 256) {
        // ---- penalty ----
        for (int i = tid; i < 1024; i += 256)
            M[1024 + i] = partial[i] + partial[NLEAF + i] + partial[2 * NLEAF + i] + partial[3 * NLEAF + i];
        __syncthreads();
        for (int n = 512; n >= 1; n >>= 1) {
            for (int u = n + tid; u < 2 * n; u += 256) M[u] = M[2 * u] + M[2 * u + 1];
            __syncthreads();
        }
        double acc = 0.0;
        for (int u = 2 + tid; u < 2048; u += 256) {
            int lvl = 31 - __clz(u);
            float a = M[u] / (M[u >> 1] + EPSV);
            a = fminf(fmaxf(a, EPSV), 1.f - EPSV);
            float term = logf(a) + logf(1.f - a);
            acc -= ldexp((double)LAMDA * 0.5, 1 - lvl) * (double)term;
        }
        dred[tid] = acc;
        __syncthreads();
        for (int s = 128; s > 0; s >>= 1) {
            if (tid < s) dred[tid] += dred[tid + s];
            __syncthreads();
        }
        if (tid == 0) out_pen[0] = (float)dred[0];
        return;
    }
    const int lane = tid & 63;
    const int w = tid >> 6;
    const int blk = blockIdx.x;
    const int m0 = blk * 64;
    const int mb = blk >> 1;
    const int mtbase = (blk & 1) * 2;
    const int s_kcl = tid >> 7, s_mti = (tid >> 6) & 1, s_ln = tid & 63;

    f32x16v acc[2][2] = {};

#define STAGE2(buf, kc0) do { \
        size_t sa16 = (((size_t)mb * 64 + (kc0) + s_kcl) * 4 + mtbase + s_mti) * 64 + s_ln; \
        gload16b(MU2 + sa16 * 8, &ldsA[buf][tid * 8]); \
        gload16b(DT2 + ((size_t)(kc0) * 512 + tid) * 8,             &ldsB[buf][tid * 8]); \
        gload16b(DT2 + ((size_t)(kc0) * 512 + 256 + tid) * 8,       &ldsB[buf][2048 + tid * 8]); \
        gload16b(DT2 + ((size_t)((kc0) + 1) * 512 + tid) * 8,       &ldsB[buf][4096 + tid * 8]); \
        gload16b(DT2 + ((size_t)((kc0) + 1) * 512 + 256 + tid) * 8, &ldsB[buf][6144 + tid * 8]); \
    } while (0)

    STAGE2(0, 0);
    for (int it = 0; it < 32; ++it) {
        const int cur = it & 1;
        if (it + 1 < 32) {
            STAGE2(cur ^ 1, 2 * (it + 1));
            asm volatile("s_waitcnt vmcnt(5)" ::: "memory");
        } else {
            asm volatile("s_waitcnt vmcnt(0)" ::: "memory");
        }
        __builtin_amdgcn_s_barrier();
        bf16x8v a[2][2], bb[2][2];
#pragma unroll
        for (int kcl = 0; kcl < 2; ++kcl)
#pragma unroll
            for (int i = 0; i < 2; ++i) {
                a[kcl][i]  = *reinterpret_cast<const bf16x8v*>(&ldsA[cur][((kcl * 2 + i) * 64 + lane) * 8]);
                bb[kcl][i] = *reinterpret_cast<const bf16x8v*>(&ldsB[cur][((kcl * 8 + 2 * w + i) * 64 + lane) * 8]);
            }
        __builtin_amdgcn_s_setprio(1);
#pragma unroll
        for (int kcl = 0; kcl < 2; ++kcl)
#pragma unroll
            for (int i = 0; i < 2; ++i)
#pragma unroll
                for (int j = 0; j < 2; ++j)
                    acc[i][j] = __builtin_amdgcn_mfma_f32_32x32x16_bf16(a[kcl][i], bb[kcl][j], acc[i][j], 0, 0, 0);
        __builtin_amdgcn_s_setprio(0);
        asm volatile("s_waitcnt lgkmcnt(0)" ::: "memory");
        __builtin_amdgcn_s_barrier();
    }
#undef STAGE2
#pragma unroll
    for (int i = 0; i < 2; ++i)
#pragma unroll
        for (int j = 0; j < 2; ++j)
#pragma unroll
            for (int r = 0; r < 16; ++r) {
                int row = m0 + i * 32 + (r & 3) + 8 * (r >> 2) + 4 * (lane >> 5);
                int col = w * 64 + j * 32 + (lane & 31);
                out1[(size_t)row * ODIM + col] = logf(acc[i][j][r]);
            }
}

// ---------------------------------------------------------------------------
extern "C" void kernel_launch(void* const* d_in, const int* in_sizes, int n_in,
                              void* d_out, int out_size, void* d_ws, size_t ws_size,
                              hipStream_t stream)
{
    (void)in_sizes; (void)n_in; (void)out_size; (void)ws_size;
    const float* data  = (const float*)d_in[0];
    const float* W     = (const float*)d_in[1];
    const float* beta  = (const float*)d_in[2];
    const float* param = (const float*)d_in[3];
    float* out = (float*)d_out;

    char* ws = (char*)d_ws;
    size_t off = 0;
    float* PT = (float*)(ws + off);                   off += (size_t)NNODES * B_ROWS * 4;   // 67.04 MB
    char* X = ws + off;                               off += 2 * 1048576 + 2 * 16777216;    // 35.65 MB
    _Float16* Wh = (_Float16*)(X);
    _Float16* Wl = (_Float16*)(X + 1048576);
    _Float16* Dh = (_Float16*)(X + 2 * 1048576);
    _Float16* Dl = (_Float16*)(X + 2 * 1048576 + 16777216);
    __hip_bfloat16* MU2 = (__hip_bfloat16*)(X + 2 * 1048576);  // overlays Dh+Dl (33.55 MB)
    __hip_bfloat16* DT2 = (__hip_bfloat16*)(ws + off); off += (size_t)ODIM * NLEAF * 2;
    float* logdist = (float*)(ws + off);              off += (size_t)NLEAF * ODIM * 4;
    float* partial = (float*)(ws + off);              off += (size_t)4 * NLEAF * 4;
    float* pval    = (float*)(ws + off);              off += (size_t)16 * B_ROWS * 4;
    int*   pidx    = (int*)(ws + off);                off += (size_t)16 * B_ROWS * 4;

    float* out_logpred = out;
    float* out_logout  = out + (size_t)B_ROWS * ODIM;
    float* out_pen     = out + 2 * (size_t)B_ROWS * ODIM;
    float* out_W       = out_pen + 1;

    prep_all<<<7428, 256, 0, stream>>>(data, W, param, Dh, Dl, Wh, Wl, out_W, logdist, DT2);

    gemm1_mfma<<<1024, 512, 0, stream>>>(Wh, Wl, Dh, Dl, W, beta, PT);

    tree_pass<<<1024, 256, 0, stream>>>(PT, MU2, pval, pidx);

    colsum_argmax<<<512, 256, 0, stream>>>(MU2, partial, pval, pidx, logdist, out_logpred);

    gemm2_penalty<<<257, 256, 0, stream>>>(MU2, DT2, out_logout, partial, out_pen);
}